// Round 1
// baseline (4791.009 us; speedup 1.0000x reference)
//
#include <hip/hip_runtime.h>
#include <hip/hip_bf16.h>
#include <cmath>

// ---------------------------------------------------------------------------
// SelectiveMagnoViT forward, f32 baseline.
// B=64, IMG=384, P=16 -> g=24, N=576, k=144, S=145, D=192, NH=3, hd=64,
// DEPTH=12, HID=768, NCLS=1000.
// ---------------------------------------------------------------------------

#define Bsz   64
#define NPATCH 576
#define KSEL  144
#define SEQ   145
#define DIM   192
#define HIDN  768

// ---------------- patch scores: 16x16 average pool of line drawing ----------
__global__ __launch_bounds__(256) void scores_kernel(const float* __restrict__ line,
                                                     float* __restrict__ scores)
{
    int gp = blockIdx.x;              // b*576 + p
    int b = gp / NPATCH, p = gp % NPATCH;
    int gy = p / 24, gx = p % 24;
    int t = threadIdx.x, py = t >> 4, px = t & 15;
    float v = line[((size_t)b * 384 + gy * 16 + py) * 384 + gx * 16 + px];
    for (int off = 32; off; off >>= 1) v += __shfl_xor(v, off);
    __shared__ float red[4];
    if ((t & 63) == 0) red[t >> 6] = v;
    __syncthreads();
    if (t == 0) scores[gp] = (red[0] + red[1] + red[2] + red[3]) * (1.f / 256.f);
}

// ---------------- exact top-k (set semantics; jax tie-break: lower idx wins) -
__global__ __launch_bounds__(256) void topk_kernel(const float* __restrict__ scores,
                                                   int* __restrict__ idx)
{
    int b = blockIdx.x;
    __shared__ float s[NPATCH];
    __shared__ unsigned char sel[NPATCH];
    for (int i = threadIdx.x; i < NPATCH; i += 256) s[i] = scores[b * NPATCH + i];
    __syncthreads();
    for (int i = threadIdx.x; i < NPATCH; i += 256) {
        float si = s[i];
        int cnt = 0;
        for (int j = 0; j < NPATCH; ++j) {
            float sj = s[j];
            cnt += (sj > si) || (sj == si && j < i);
        }
        sel[i] = (cnt < KSEL) ? 1 : 0;
    }
    __syncthreads();
    if (threadIdx.x == 0) {
        int slot = 0;
        for (int i = 0; i < NPATCH; ++i)
            if (sel[i]) idx[b * KSEL + slot++] = i;
    }
}

// ---------------- gather selected patches into (B*144, 768) -----------------
__global__ __launch_bounds__(256) void gather_kernel(const float* __restrict__ magno,
                                                     const int* __restrict__ idx,
                                                     float* __restrict__ selp)
{
    int bs = blockIdx.x;              // b*144 + s
    int b = bs / KSEL;
    int pi = idx[bs];
    int gy = pi / 24, gx = pi % 24;
    int t = threadIdx.x, py = t >> 4, px = t & 15;
    size_t src = ((size_t)b * 3 * 384 + gy * 16 + py) * 384 + gx * 16 + px;
    float* dst = &selp[(size_t)bs * 768];
#pragma unroll
    for (int c = 0; c < 3; ++c)
        dst[c * 256 + t] = magno[src + (size_t)c * 384 * 384];
}

// ---------------- conv_w (192,768) -> (768,192) -----------------------------
__global__ __launch_bounds__(256) void transpose_conv(const float* __restrict__ w,
                                                      float* __restrict__ wt)
{
    int i = blockIdx.x * 256 + threadIdx.x;   // 768*192 = 147456 = 576*256
    int k = i / DIM, n = i % DIM;
    wt[i] = w[n * 768 + k];
}

// ---------------- cls token init --------------------------------------------
__global__ void cls_kernel(const float* __restrict__ cls, const float* __restrict__ pos,
                           float* __restrict__ h)
{
    int b = blockIdx.x, t = threadIdx.x;      // 192 threads
    h[(size_t)b * SEQ * DIM + t] = cls[t] + pos[t];
}

// ---------------- LayerNorm over D=192, one wave per token ------------------
__global__ __launch_bounds__(256) void ln_kernel(const float* __restrict__ x,
                                                 const float* __restrict__ s,
                                                 const float* __restrict__ bia,
                                                 float* __restrict__ y, int ntok)
{
    int w = threadIdx.x >> 6, lane = threadIdx.x & 63;
    int tok = blockIdx.x * 4 + w;
    if (tok >= ntok) return;
    const float* xp = &x[(size_t)tok * DIM];
    float x0 = xp[lane], x1 = xp[lane + 64], x2 = xp[lane + 128];
    float sum = x0 + x1 + x2;
    for (int off = 32; off; off >>= 1) sum += __shfl_xor(sum, off);
    float mean = sum * (1.f / 192.f);
    float d0 = x0 - mean, d1 = x1 - mean, d2 = x2 - mean;
    float vs = d0 * d0 + d1 * d1 + d2 * d2;
    for (int off = 32; off; off >>= 1) vs += __shfl_xor(vs, off);
    float rs = rsqrtf(vs * (1.f / 192.f) + 1e-6f);
    float* yp = &y[(size_t)tok * DIM];
    yp[lane]       = d0 * rs * s[lane]       + bia[lane];
    yp[lane + 64]  = d1 * rs * s[lane + 64]  + bia[lane + 64];
    yp[lane + 128] = d2 * rs * s[lane + 128] + bia[lane + 128];
}

// ---------------- generic tiled f32 GEMM: C = A(M,K) @ W(K,N) + bias --------
// MODE 0: store   MODE 1: C += (residual)   MODE 2: gelu store
// MODE 3: patch embed epilogue (pos add + shifted token store)
template <int MODE>
__global__ __launch_bounds__(256) void gemm_f32(const float* __restrict__ A,
                                                const float* __restrict__ W,
                                                const float* __restrict__ bias,
                                                float* __restrict__ C,
                                                int M, int N, int K,
                                                const int* __restrict__ selidx,
                                                const float* __restrict__ pos)
{
    __shared__ float As[16][64];
    __shared__ float Ws[16][64];
    const int tid = threadIdx.x;
    const int tx = tid & 15, ty = tid >> 4;
    const int m0 = blockIdx.y * 64, n0 = blockIdx.x * 64;
    const int ar = tid >> 2;           // 0..63  (A row within tile)
    const int ac = (tid & 3) * 4;      // 0,4,8,12
    const int wr = tid >> 4;           // 0..15  (W row within tile)
    const int wc = (tid & 15) * 4;     // 0..60
    float acc[4][4] = {};
    for (int k0 = 0; k0 < K; k0 += 16) {
        float4 av = *reinterpret_cast<const float4*>(&A[(size_t)(m0 + ar) * K + k0 + ac]);
        float4 wv = *reinterpret_cast<const float4*>(&W[(size_t)(k0 + wr) * N + n0 + wc]);
        As[ac + 0][ar] = av.x; As[ac + 1][ar] = av.y;
        As[ac + 2][ar] = av.z; As[ac + 3][ar] = av.w;
        *reinterpret_cast<float4*>(&Ws[wr][wc]) = wv;
        __syncthreads();
#pragma unroll
        for (int kk = 0; kk < 16; ++kk) {
            float4 a = *reinterpret_cast<const float4*>(&As[kk][ty * 4]);
            float4 bv = *reinterpret_cast<const float4*>(&Ws[kk][tx * 4]);
            float aa[4] = {a.x, a.y, a.z, a.w};
            float bb[4] = {bv.x, bv.y, bv.z, bv.w};
#pragma unroll
            for (int i = 0; i < 4; ++i)
#pragma unroll
                for (int j = 0; j < 4; ++j)
                    acc[i][j] = fmaf(aa[i], bb[j], acc[i][j]);
        }
        __syncthreads();
    }
#pragma unroll
    for (int i = 0; i < 4; ++i) {
        int row = m0 + ty * 4 + i;
#pragma unroll
        for (int j = 0; j < 4; ++j) {
            int col = n0 + tx * 4 + j;
            float v = acc[i][j] + bias[col];
            if (MODE == 0) {
                C[(size_t)row * N + col] = v;
            } else if (MODE == 1) {
                C[(size_t)row * N + col] += v;
            } else if (MODE == 2) {
                C[(size_t)row * N + col] = 0.5f * v * (1.f + erff(v * 0.70710678118654752f));
            } else {
                int bb2 = row / KSEL, ss = row % KSEL;
                int pi = selidx[row];
                v += pos[(size_t)(1 + pi) * DIM + col];
                C[((size_t)bb2 * SEQ + 1 + ss) * DIM + col] = v;
            }
        }
    }
}

// ---------------- attention: one block per (b, head) ------------------------
__global__ __launch_bounds__(256) void attn_kernel(const float* __restrict__ qkv,
                                                   float* __restrict__ o)
{
    const int bh = blockIdx.x;        // b*3 + h
    const int b = bh / 3, h = bh % 3;
    __shared__ float Ks[SEQ * 65];
    __shared__ float Vs[SEQ * 65];
    __shared__ float Ps[4][160];
    const int tid = threadIdx.x;
    const size_t base = (size_t)b * SEQ * 576;
    for (int t = tid; t < SEQ * 64; t += 256) {
        int r = t >> 6, c = t & 63;
        const float* src = &qkv[base + (size_t)r * 576 + h * 64 + c];
        Ks[r * 65 + c] = src[192];
        Vs[r * 65 + c] = src[384];
    }
    __syncthreads();
    const int w = tid >> 6, lane = tid & 63;
    for (int qi = w; qi < SEQ; qi += 4) {
        float qreg = qkv[base + (size_t)qi * 576 + h * 64 + lane];
        float s0 = 0.f, s1 = 0.f, s2 = 0.f;
        const int j0 = lane, j1 = lane + 64, j2 = lane + 128;
        const bool v2 = (j2 < SEQ);
#pragma unroll 16
        for (int d = 0; d < 64; ++d) {
            float qd = __shfl(qreg, d);
            s0 = fmaf(qd, Ks[j0 * 65 + d], s0);
            s1 = fmaf(qd, Ks[j1 * 65 + d], s1);
            if (v2) s2 = fmaf(qd, Ks[j2 * 65 + d], s2);
        }
        s0 *= 0.125f; s1 *= 0.125f; s2 = v2 ? s2 * 0.125f : -1e30f;
        float m = fmaxf(fmaxf(s0, s1), s2);
        for (int off = 32; off; off >>= 1) m = fmaxf(m, __shfl_xor(m, off));
        float p0 = __expf(s0 - m), p1 = __expf(s1 - m);
        float p2 = v2 ? __expf(s2 - m) : 0.f;
        float sum = p0 + p1 + p2;
        for (int off = 32; off; off >>= 1) sum += __shfl_xor(sum, off);
        float inv = 1.f / sum;
        Ps[w][j0] = p0; Ps[w][j1] = p1;
        if (v2) Ps[w][j2] = p2;
        float acc = 0.f;
        for (int j = 0; j < SEQ; ++j)
            acc = fmaf(Ps[w][j], Vs[j * 65 + lane], acc);
        o[((size_t)b * SEQ + qi) * DIM + h * 64 + lane] = acc * inv;
    }
}

// ---------------- head: final LN of cls + (64,192)@(192,1000) ---------------
__global__ __launch_bounds__(256) void head_kernel(const float* __restrict__ h,
                                                   const float* __restrict__ nfs,
                                                   const float* __restrict__ nfb,
                                                   const float* __restrict__ hw,
                                                   const float* __restrict__ hb,
                                                   float* __restrict__ out)
{
    int b = blockIdx.x, t = threadIdx.x;
    __shared__ float y[DIM];
    __shared__ float red[4];
    float x = (t < DIM) ? h[(size_t)b * SEQ * DIM + t] : 0.f;
    float sum = x;
    for (int off = 32; off; off >>= 1) sum += __shfl_xor(sum, off);
    if ((t & 63) == 0) red[t >> 6] = sum;
    __syncthreads();
    float mean = (red[0] + red[1] + red[2] + red[3]) * (1.f / 192.f);
    __syncthreads();
    float d = (t < DIM) ? (x - mean) : 0.f;
    float v = d * d;
    for (int off = 32; off; off >>= 1) v += __shfl_xor(v, off);
    if ((t & 63) == 0) red[t >> 6] = v;
    __syncthreads();
    float var = (red[0] + red[1] + red[2] + red[3]) * (1.f / 192.f);
    float rs = rsqrtf(var + 1e-6f);
    if (t < DIM) y[t] = d * rs * nfs[t] + nfb[t];
    __syncthreads();
    for (int n = t; n < 1000; n += 256) {
        float acc = hb[n];
#pragma unroll 8
        for (int k = 0; k < DIM; ++k)
            acc = fmaf(y[k], hw[(size_t)k * 1000 + n], acc);
        out[(size_t)b * 1000 + n] = acc;
    }
}

// ---------------------------------------------------------------------------
extern "C" void kernel_launch(void* const* d_in, const int* in_sizes, int n_in,
                              void* d_out, int out_size, void* d_ws, size_t ws_size,
                              hipStream_t stream)
{
    const float* magno  = (const float*)d_in[0];
    const float* line   = (const float*)d_in[1];
    const float* conv_w = (const float*)d_in[2];
    const float* conv_b = (const float*)d_in[3];
    const float* pos    = (const float*)d_in[4];
    const float* cls    = (const float*)d_in[5];
    const float* ln1_s  = (const float*)d_in[6];
    const float* ln1_b  = (const float*)d_in[7];
    const float* qkv_w  = (const float*)d_in[8];
    const float* qkv_b  = (const float*)d_in[9];
    const float* proj_w = (const float*)d_in[10];
    const float* proj_b = (const float*)d_in[11];
    const float* ln2_s  = (const float*)d_in[12];
    const float* ln2_b  = (const float*)d_in[13];
    const float* fc1_w  = (const float*)d_in[14];
    const float* fc1_b  = (const float*)d_in[15];
    const float* fc2_w  = (const float*)d_in[16];
    const float* fc2_b  = (const float*)d_in[17];
    const float* normf_s = (const float*)d_in[18];
    const float* normf_b = (const float*)d_in[19];
    const float* head_w = (const float*)d_in[20];
    const float* head_b = (const float*)d_in[21];
    float* out = (float*)d_out;
    (void)in_sizes; (void)n_in; (void)out_size; (void)ws_size;

    // workspace layout (bytes, 256-aligned); total 64,290,816 B ≈ 61.3 MB
    char* ws = (char*)d_ws;
    int*   idx  = (int*)  (ws + 0);          // 64*144*4           = 147456
    float* h    = (float*)(ws + 147456);     // 64*145*192*4       = 7127040
    float* y    = (float*)(ws + 7274496);    // same size
    float* qkv  = (float*)(ws + 14401536);   // 64*145*576*4       = 21381120
    float* tbuf = (float*)(ws + 35782656);   // 64*145*768*4       = 28508160
    float* scoresbuf = qkv;                  // alias (used before qkv)
    float* convT     = y;                    // alias (used before y)
    float* selp      = tbuf;                 // alias (used before tbuf)

    scores_kernel<<<Bsz * NPATCH, 256, 0, stream>>>(line, scoresbuf);
    topk_kernel<<<Bsz, 256, 0, stream>>>(scoresbuf, idx);
    gather_kernel<<<Bsz * KSEL, 256, 0, stream>>>(magno, idx, selp);
    transpose_conv<<<576, 256, 0, stream>>>(conv_w, convT);
    cls_kernel<<<Bsz, DIM, 0, stream>>>(cls, pos, h);
    // patch embed: (9216,768)@(768,192) -> tokens 1..144 of h (with pos add)
    gemm_f32<3><<<dim3(3, 144), 256, 0, stream>>>(selp, convT, conv_b, h,
                                                  9216, DIM, 768, idx, pos);

    const int ntok = Bsz * SEQ;              // 9280 = 145*64
    for (int l = 0; l < 12; ++l) {
        ln_kernel<<<ntok / 4, 256, 0, stream>>>(h, ln1_s + l * DIM, ln1_b + l * DIM, y, ntok);
        gemm_f32<0><<<dim3(9, 145), 256, 0, stream>>>(y, qkv_w + (size_t)l * DIM * 576,
                                                      qkv_b + l * 576, qkv,
                                                      ntok, 576, DIM, nullptr, nullptr);
        attn_kernel<<<Bsz * 3, 256, 0, stream>>>(qkv, y);
        gemm_f32<1><<<dim3(3, 145), 256, 0, stream>>>(y, proj_w + (size_t)l * DIM * DIM,
                                                      proj_b + l * DIM, h,
                                                      ntok, DIM, DIM, nullptr, nullptr);
        ln_kernel<<<ntok / 4, 256, 0, stream>>>(h, ln2_s + l * DIM, ln2_b + l * DIM, y, ntok);
        gemm_f32<2><<<dim3(12, 145), 256, 0, stream>>>(y, fc1_w + (size_t)l * DIM * HIDN,
                                                       fc1_b + l * HIDN, tbuf,
                                                       ntok, HIDN, DIM, nullptr, nullptr);
        gemm_f32<1><<<dim3(3, 145), 256, 0, stream>>>(tbuf, fc2_w + (size_t)l * HIDN * DIM,
                                                      fc2_b + l * DIM, h,
                                                      ntok, DIM, HIDN, nullptr, nullptr);
    }
    head_kernel<<<Bsz, 256, 0, stream>>>(h, normf_s, normf_b, head_w, head_b, out);
}

// Round 2
// 3001.014 us; speedup vs baseline: 1.5965x; 1.5965x over previous
//
#include <hip/hip_runtime.h>
#include <hip/hip_bf16.h>
#include <cmath>

// ---------------------------------------------------------------------------
// SelectiveMagnoViT forward. Round 1: attention rewritten as register-blocked
// GEMM phases (was DS-pipe-bound at 192 blocks / 228us per layer).
// B=64, IMG=384, P=16 -> g=24, N=576, k=144, S=145, D=192, NH=3, hd=64,
// DEPTH=12, HID=768, NCLS=1000.
// ---------------------------------------------------------------------------

#define Bsz   64
#define NPATCH 576
#define KSEL  144
#define SEQ   145
#define DIM   192
#define HIDN  768

// ---------------- patch scores: 16x16 average pool of line drawing ----------
__global__ __launch_bounds__(256) void scores_kernel(const float* __restrict__ line,
                                                     float* __restrict__ scores)
{
    int gp = blockIdx.x;              // b*576 + p
    int b = gp / NPATCH, p = gp % NPATCH;
    int gy = p / 24, gx = p % 24;
    int t = threadIdx.x, py = t >> 4, px = t & 15;
    float v = line[((size_t)b * 384 + gy * 16 + py) * 384 + gx * 16 + px];
    for (int off = 32; off; off >>= 1) v += __shfl_xor(v, off);
    __shared__ float red[4];
    if ((t & 63) == 0) red[t >> 6] = v;
    __syncthreads();
    if (t == 0) scores[gp] = (red[0] + red[1] + red[2] + red[3]) * (1.f / 256.f);
}

// ---------------- exact top-k (set semantics; jax tie-break: lower idx wins) -
__global__ __launch_bounds__(256) void topk_kernel(const float* __restrict__ scores,
                                                   int* __restrict__ idx)
{
    int b = blockIdx.x;
    __shared__ float s[NPATCH];
    __shared__ unsigned char sel[NPATCH];
    for (int i = threadIdx.x; i < NPATCH; i += 256) s[i] = scores[b * NPATCH + i];
    __syncthreads();
    for (int i = threadIdx.x; i < NPATCH; i += 256) {
        float si = s[i];
        int cnt = 0;
        for (int j = 0; j < NPATCH; ++j) {
            float sj = s[j];
            cnt += (sj > si) || (sj == si && j < i);
        }
        sel[i] = (cnt < KSEL) ? 1 : 0;
    }
    __syncthreads();
    if (threadIdx.x == 0) {
        int slot = 0;
        for (int i = 0; i < NPATCH; ++i)
            if (sel[i]) idx[b * KSEL + slot++] = i;
    }
}

// ---------------- gather selected patches into (B*144, 768) -----------------
__global__ __launch_bounds__(256) void gather_kernel(const float* __restrict__ magno,
                                                     const int* __restrict__ idx,
                                                     float* __restrict__ selp)
{
    int bs = blockIdx.x;              // b*144 + s
    int b = bs / KSEL;
    int pi = idx[bs];
    int gy = pi / 24, gx = pi % 24;
    int t = threadIdx.x, py = t >> 4, px = t & 15;
    size_t src = ((size_t)b * 3 * 384 + gy * 16 + py) * 384 + gx * 16 + px;
    float* dst = &selp[(size_t)bs * 768];
#pragma unroll
    for (int c = 0; c < 3; ++c)
        dst[c * 256 + t] = magno[src + (size_t)c * 384 * 384];
}

// ---------------- conv_w (192,768) -> (768,192) -----------------------------
__global__ __launch_bounds__(256) void transpose_conv(const float* __restrict__ w,
                                                      float* __restrict__ wt)
{
    int i = blockIdx.x * 256 + threadIdx.x;   // 768*192 = 147456 = 576*256
    int k = i / DIM, n = i % DIM;
    wt[i] = w[n * 768 + k];
}

// ---------------- cls token init --------------------------------------------
__global__ void cls_kernel(const float* __restrict__ cls, const float* __restrict__ pos,
                           float* __restrict__ h)
{
    int b = blockIdx.x, t = threadIdx.x;      // 192 threads
    h[(size_t)b * SEQ * DIM + t] = cls[t] + pos[t];
}

// ---------------- LayerNorm over D=192, one wave per token ------------------
__global__ __launch_bounds__(256) void ln_kernel(const float* __restrict__ x,
                                                 const float* __restrict__ s,
                                                 const float* __restrict__ bia,
                                                 float* __restrict__ y, int ntok)
{
    int w = threadIdx.x >> 6, lane = threadIdx.x & 63;
    int tok = blockIdx.x * 4 + w;
    if (tok >= ntok) return;
    const float* xp = &x[(size_t)tok * DIM];
    float x0 = xp[lane], x1 = xp[lane + 64], x2 = xp[lane + 128];
    float sum = x0 + x1 + x2;
    for (int off = 32; off; off >>= 1) sum += __shfl_xor(sum, off);
    float mean = sum * (1.f / 192.f);
    float d0 = x0 - mean, d1 = x1 - mean, d2 = x2 - mean;
    float vs = d0 * d0 + d1 * d1 + d2 * d2;
    for (int off = 32; off; off >>= 1) vs += __shfl_xor(vs, off);
    float rs = rsqrtf(vs * (1.f / 192.f) + 1e-6f);
    float* yp = &y[(size_t)tok * DIM];
    yp[lane]       = d0 * rs * s[lane]       + bia[lane];
    yp[lane + 64]  = d1 * rs * s[lane + 64]  + bia[lane + 64];
    yp[lane + 128] = d2 * rs * s[lane + 128] + bia[lane + 128];
}

// ---------------- generic tiled f32 GEMM: C = A(M,K) @ W(K,N) + bias --------
// MODE 0: store   MODE 1: C += (residual)   MODE 2: gelu store
// MODE 3: patch embed epilogue (pos add + shifted token store)
template <int MODE>
__global__ __launch_bounds__(256) void gemm_f32(const float* __restrict__ A,
                                                const float* __restrict__ W,
                                                const float* __restrict__ bias,
                                                float* __restrict__ C,
                                                int M, int N, int K,
                                                const int* __restrict__ selidx,
                                                const float* __restrict__ pos)
{
    __shared__ float As[16][64];
    __shared__ float Ws[16][64];
    const int tid = threadIdx.x;
    const int tx = tid & 15, ty = tid >> 4;
    const int m0 = blockIdx.y * 64, n0 = blockIdx.x * 64;
    const int ar = tid >> 2;           // 0..63  (A row within tile)
    const int ac = (tid & 3) * 4;      // 0,4,8,12
    const int wr = tid >> 4;           // 0..15  (W row within tile)
    const int wc = (tid & 15) * 4;     // 0..60
    float acc[4][4] = {};
    for (int k0 = 0; k0 < K; k0 += 16) {
        float4 av = *reinterpret_cast<const float4*>(&A[(size_t)(m0 + ar) * K + k0 + ac]);
        float4 wv = *reinterpret_cast<const float4*>(&W[(size_t)(k0 + wr) * N + n0 + wc]);
        As[ac + 0][ar] = av.x; As[ac + 1][ar] = av.y;
        As[ac + 2][ar] = av.z; As[ac + 3][ar] = av.w;
        *reinterpret_cast<float4*>(&Ws[wr][wc]) = wv;
        __syncthreads();
#pragma unroll
        for (int kk = 0; kk < 16; ++kk) {
            float4 a = *reinterpret_cast<const float4*>(&As[kk][ty * 4]);
            float4 bv = *reinterpret_cast<const float4*>(&Ws[kk][tx * 4]);
            float aa[4] = {a.x, a.y, a.z, a.w};
            float bb[4] = {bv.x, bv.y, bv.z, bv.w};
#pragma unroll
            for (int i = 0; i < 4; ++i)
#pragma unroll
                for (int j = 0; j < 4; ++j)
                    acc[i][j] = fmaf(aa[i], bb[j], acc[i][j]);
        }
        __syncthreads();
    }
#pragma unroll
    for (int i = 0; i < 4; ++i) {
        int row = m0 + ty * 4 + i;
#pragma unroll
        for (int j = 0; j < 4; ++j) {
            int col = n0 + tx * 4 + j;
            float v = acc[i][j] + bias[col];
            if (MODE == 0) {
                C[(size_t)row * N + col] = v;
            } else if (MODE == 1) {
                C[(size_t)row * N + col] += v;
            } else if (MODE == 2) {
                C[(size_t)row * N + col] = 0.5f * v * (1.f + erff(v * 0.70710678118654752f));
            } else {
                int bb2 = row / KSEL, ss = row % KSEL;
                int pi = selidx[row];
                v += pos[(size_t)(1 + pi) * DIM + col];
                C[((size_t)bb2 * SEQ + 1 + ss) * DIM + col] = v;
            }
        }
    }
}

// ---------------- attention v2: block = (b, h, 32-query tile) ---------------
// Phase 1 (scores): S(32x192) = Q(32x64) @ K^T, thread = 2q x 12k, f32.
// Phase 2: wave-parallel softmax over tx lanes (rows split 16-wide x 12 regs).
// Phase 3 (PV): O(32x64) = P @ V, P from LDS, V float4 direct from global/L2.
__global__ __launch_bounds__(256) void attn2_kernel(const float* __restrict__ qkv,
                                                    float* __restrict__ o)
{
    __shared__ float Qs[64][34];    // Qs[d][q]
    __shared__ float Kt[64][196];   // Kt[d][key], keys >=145 zero
    __shared__ float Ps[SEQ][34];   // Ps[key][q], normalized probs
    const int b = blockIdx.y;
    const int h = blockIdx.x / 5, qt = blockIdx.x % 5;
    const int tid = threadIdx.x;
    const int tx = tid & 15, ty = tid >> 4;
    const size_t base = (size_t)b * SEQ * 576 + h * 64;

    // stage Q transposed (coalesced global read, 2-way-free LDS write)
    for (int e = tid; e < 32 * 64; e += 256) {
        int q = e >> 6, d = e & 63;
        int tok = qt * 32 + q;
        Qs[d][q] = (tok < SEQ) ? qkv[base + (size_t)tok * 576 + d] : 0.f;
    }
    // stage K transposed, zero-padded to 196 keys
    for (int e = tid; e < 196 * 64; e += 256) {
        int kk = e >> 6, d = e & 63;
        Kt[d][kk] = (kk < SEQ) ? qkv[base + (size_t)kk * 576 + 192 + d] : 0.f;
    }
    __syncthreads();

    // ---- scores: 2 queries x 12 keys per thread --------------------------
    float s[2][12] = {};
#pragma unroll 8
    for (int d = 0; d < 64; ++d) {
        float q0 = Qs[d][2 * ty];
        float q1 = Qs[d][2 * ty + 1];
#pragma unroll
        for (int p = 0; p < 3; ++p) {
            float4 kv = *reinterpret_cast<const float4*>(&Kt[d][p * 64 + 4 * tx]);
            s[0][p * 4 + 0] = fmaf(q0, kv.x, s[0][p * 4 + 0]);
            s[0][p * 4 + 1] = fmaf(q0, kv.y, s[0][p * 4 + 1]);
            s[0][p * 4 + 2] = fmaf(q0, kv.z, s[0][p * 4 + 2]);
            s[0][p * 4 + 3] = fmaf(q0, kv.w, s[0][p * 4 + 3]);
            s[1][p * 4 + 0] = fmaf(q1, kv.x, s[1][p * 4 + 0]);
            s[1][p * 4 + 1] = fmaf(q1, kv.y, s[1][p * 4 + 1]);
            s[1][p * 4 + 2] = fmaf(q1, kv.z, s[1][p * 4 + 2]);
            s[1][p * 4 + 3] = fmaf(q1, kv.w, s[1][p * 4 + 3]);
        }
    }

    // ---- softmax: scale, mask padded keys, reduce across 16 tx lanes -----
#pragma unroll
    for (int i = 0; i < 2; ++i) {
#pragma unroll
        for (int e = 0; e < 12; ++e) {
            int key = (e >> 2) * 64 + 4 * tx + (e & 3);
            s[i][e] = (key < SEQ) ? s[i][e] * 0.125f : -1e30f;
        }
        float m = -1e30f;
#pragma unroll
        for (int e = 0; e < 12; ++e) m = fmaxf(m, s[i][e]);
        for (int off = 1; off < 16; off <<= 1) m = fmaxf(m, __shfl_xor(m, off));
        float l = 0.f;
#pragma unroll
        for (int e = 0; e < 12; ++e) { s[i][e] = __expf(s[i][e] - m); l += s[i][e]; }
        for (int off = 1; off < 16; off <<= 1) l += __shfl_xor(l, off);
        float inv = 1.f / l;
#pragma unroll
        for (int e = 0; e < 12; ++e) s[i][e] *= inv;
    }

    // ---- write normalized P to LDS ---------------------------------------
#pragma unroll
    for (int i = 0; i < 2; ++i)
#pragma unroll
        for (int e = 0; e < 12; ++e) {
            int key = (e >> 2) * 64 + 4 * tx + (e & 3);
            if (key < SEQ) Ps[key][2 * ty + i] = s[i][e];
        }
    __syncthreads();

    // ---- PV: thread = 2q x 4d; V read float4-coalesced from global (L2) --
    float acc[2][4] = {};
#pragma unroll 8
    for (int k = 0; k < SEQ; ++k) {
        float4 vv = *reinterpret_cast<const float4*>(&qkv[base + (size_t)k * 576 + 384 + 4 * tx]);
        float p0 = Ps[k][2 * ty];
        float p1 = Ps[k][2 * ty + 1];
        acc[0][0] = fmaf(p0, vv.x, acc[0][0]);
        acc[0][1] = fmaf(p0, vv.y, acc[0][1]);
        acc[0][2] = fmaf(p0, vv.z, acc[0][2]);
        acc[0][3] = fmaf(p0, vv.w, acc[0][3]);
        acc[1][0] = fmaf(p1, vv.x, acc[1][0]);
        acc[1][1] = fmaf(p1, vv.y, acc[1][1]);
        acc[1][2] = fmaf(p1, vv.z, acc[1][2]);
        acc[1][3] = fmaf(p1, vv.w, acc[1][3]);
    }
#pragma unroll
    for (int i = 0; i < 2; ++i) {
        int tok = qt * 32 + 2 * ty + i;
        if (tok < SEQ) {
            float4 ov = make_float4(acc[i][0], acc[i][1], acc[i][2], acc[i][3]);
            *reinterpret_cast<float4*>(&o[((size_t)b * SEQ + tok) * DIM + h * 64 + 4 * tx]) = ov;
        }
    }
}

// ---------------- head: final LN of cls + (64,192)@(192,1000) ---------------
__global__ __launch_bounds__(256) void head_kernel(const float* __restrict__ h,
                                                   const float* __restrict__ nfs,
                                                   const float* __restrict__ nfb,
                                                   const float* __restrict__ hw,
                                                   const float* __restrict__ hb,
                                                   float* __restrict__ out)
{
    int b = blockIdx.x, t = threadIdx.x;
    __shared__ float y[DIM];
    __shared__ float red[4];
    float x = (t < DIM) ? h[(size_t)b * SEQ * DIM + t] : 0.f;
    float sum = x;
    for (int off = 32; off; off >>= 1) sum += __shfl_xor(sum, off);
    if ((t & 63) == 0) red[t >> 6] = sum;
    __syncthreads();
    float mean = (red[0] + red[1] + red[2] + red[3]) * (1.f / 192.f);
    __syncthreads();
    float d = (t < DIM) ? (x - mean) : 0.f;
    float v = d * d;
    for (int off = 32; off; off >>= 1) v += __shfl_xor(v, off);
    if ((t & 63) == 0) red[t >> 6] = v;
    __syncthreads();
    float var = (red[0] + red[1] + red[2] + red[3]) * (1.f / 192.f);
    float rs = rsqrtf(var + 1e-6f);
    if (t < DIM) y[t] = d * rs * nfs[t] + nfb[t];
    __syncthreads();
    for (int n = t; n < 1000; n += 256) {
        float acc = hb[n];
#pragma unroll 8
        for (int k = 0; k < DIM; ++k)
            acc = fmaf(y[k], hw[(size_t)k * 1000 + n], acc);
        out[(size_t)b * 1000 + n] = acc;
    }
}

// ---------------------------------------------------------------------------
extern "C" void kernel_launch(void* const* d_in, const int* in_sizes, int n_in,
                              void* d_out, int out_size, void* d_ws, size_t ws_size,
                              hipStream_t stream)
{
    const float* magno  = (const float*)d_in[0];
    const float* line   = (const float*)d_in[1];
    const float* conv_w = (const float*)d_in[2];
    const float* conv_b = (const float*)d_in[3];
    const float* pos    = (const float*)d_in[4];
    const float* cls    = (const float*)d_in[5];
    const float* ln1_s  = (const float*)d_in[6];
    const float* ln1_b  = (const float*)d_in[7];
    const float* qkv_w  = (const float*)d_in[8];
    const float* qkv_b  = (const float*)d_in[9];
    const float* proj_w = (const float*)d_in[10];
    const float* proj_b = (const float*)d_in[11];
    const float* ln2_s  = (const float*)d_in[12];
    const float* ln2_b  = (const float*)d_in[13];
    const float* fc1_w  = (const float*)d_in[14];
    const float* fc1_b  = (const float*)d_in[15];
    const float* fc2_w  = (const float*)d_in[16];
    const float* fc2_b  = (const float*)d_in[17];
    const float* normf_s = (const float*)d_in[18];
    const float* normf_b = (const float*)d_in[19];
    const float* head_w = (const float*)d_in[20];
    const float* head_b = (const float*)d_in[21];
    float* out = (float*)d_out;
    (void)in_sizes; (void)n_in; (void)out_size; (void)ws_size;

    // workspace layout (bytes, 256-aligned); total 64,290,816 B ≈ 61.3 MB
    char* ws = (char*)d_ws;
    int*   idx  = (int*)  (ws + 0);          // 64*144*4           = 147456
    float* h    = (float*)(ws + 147456);     // 64*145*192*4       = 7127040
    float* y    = (float*)(ws + 7274496);    // same size
    float* qkv  = (float*)(ws + 14401536);   // 64*145*576*4       = 21381120
    float* tbuf = (float*)(ws + 35782656);   // 64*145*768*4       = 28508160
    float* scoresbuf = qkv;                  // alias (used before qkv)
    float* convT     = y;                    // alias (used before y)
    float* selp      = tbuf;                 // alias (used before tbuf)

    scores_kernel<<<Bsz * NPATCH, 256, 0, stream>>>(line, scoresbuf);
    topk_kernel<<<Bsz, 256, 0, stream>>>(scoresbuf, idx);
    gather_kernel<<<Bsz * KSEL, 256, 0, stream>>>(magno, idx, selp);
    transpose_conv<<<576, 256, 0, stream>>>(conv_w, convT);
    cls_kernel<<<Bsz, DIM, 0, stream>>>(cls, pos, h);
    // patch embed: (9216,768)@(768,192) -> tokens 1..144 of h (with pos add)
    gemm_f32<3><<<dim3(3, 144), 256, 0, stream>>>(selp, convT, conv_b, h,
                                                  9216, DIM, 768, idx, pos);

    const int ntok = Bsz * SEQ;              // 9280 = 145*64
    for (int l = 0; l < 12; ++l) {
        ln_kernel<<<ntok / 4, 256, 0, stream>>>(h, ln1_s + l * DIM, ln1_b + l * DIM, y, ntok);
        gemm_f32<0><<<dim3(9, 145), 256, 0, stream>>>(y, qkv_w + (size_t)l * DIM * 576,
                                                      qkv_b + l * 576, qkv,
                                                      ntok, 576, DIM, nullptr, nullptr);
        attn2_kernel<<<dim3(15, Bsz), 256, 0, stream>>>(qkv, y);
        gemm_f32<1><<<dim3(3, 145), 256, 0, stream>>>(y, proj_w + (size_t)l * DIM * DIM,
                                                      proj_b + l * DIM, h,
                                                      ntok, DIM, DIM, nullptr, nullptr);
        ln_kernel<<<ntok / 4, 256, 0, stream>>>(h, ln2_s + l * DIM, ln2_b + l * DIM, y, ntok);
        gemm_f32<2><<<dim3(12, 145), 256, 0, stream>>>(y, fc1_w + (size_t)l * DIM * HIDN,
                                                       fc1_b + l * HIDN, tbuf,
                                                       ntok, HIDN, DIM, nullptr, nullptr);
        gemm_f32<1><<<dim3(3, 145), 256, 0, stream>>>(tbuf, fc2_w + (size_t)l * HIDN * DIM,
                                                      fc2_b + l * DIM, h,
                                                      ntok, DIM, HIDN, nullptr, nullptr);
    }
    head_kernel<<<Bsz, 256, 0, stream>>>(h, normf_s, normf_b, head_w, head_b, out);
}

// Round 3
// 1627.847 us; speedup vs baseline: 2.9432x; 1.8435x over previous
//
#include <hip/hip_runtime.h>
#include <hip/hip_bf16.h>
#include <cmath>

// ---------------------------------------------------------------------------
// SelectiveMagnoViT forward. Round 2: all GEMMs -> bf16 MFMA (16x16x32),
// weights pre-transposed+converted to bf16 [N][K] per call, activations
// produced in bf16. Residual stream and qkv stay f32.
// ---------------------------------------------------------------------------

#define Bsz   64
#define NPATCH 576
#define KSEL  144
#define SEQ   145
#define DIM   192
#define HIDN  768

typedef __bf16 bf16x8 __attribute__((ext_vector_type(8)));
typedef float  f32x4  __attribute__((ext_vector_type(4)));

// ---------------- patch scores: 16x16 average pool of line drawing ----------
__global__ __launch_bounds__(256) void scores_kernel(const float* __restrict__ line,
                                                     float* __restrict__ scores)
{
    int gp = blockIdx.x;              // b*576 + p
    int b = gp / NPATCH, p = gp % NPATCH;
    int gy = p / 24, gx = p % 24;
    int t = threadIdx.x, py = t >> 4, px = t & 15;
    float v = line[((size_t)b * 384 + gy * 16 + py) * 384 + gx * 16 + px];
    for (int off = 32; off; off >>= 1) v += __shfl_xor(v, off);
    __shared__ float red[4];
    if ((t & 63) == 0) red[t >> 6] = v;
    __syncthreads();
    if (t == 0) scores[gp] = (red[0] + red[1] + red[2] + red[3]) * (1.f / 256.f);
}

// ---------------- exact top-k (set semantics; jax tie-break: lower idx wins) -
__global__ __launch_bounds__(256) void topk_kernel(const float* __restrict__ scores,
                                                   int* __restrict__ idx)
{
    int b = blockIdx.x;
    __shared__ float s[NPATCH];
    __shared__ unsigned char sel[NPATCH];
    for (int i = threadIdx.x; i < NPATCH; i += 256) s[i] = scores[b * NPATCH + i];
    __syncthreads();
    for (int i = threadIdx.x; i < NPATCH; i += 256) {
        float si = s[i];
        int cnt = 0;
        for (int j = 0; j < NPATCH; ++j) {
            float sj = s[j];
            cnt += (sj > si) || (sj == si && j < i);
        }
        sel[i] = (cnt < KSEL) ? 1 : 0;
    }
    __syncthreads();
    if (threadIdx.x == 0) {
        int slot = 0;
        for (int i = 0; i < NPATCH; ++i)
            if (sel[i]) idx[b * KSEL + slot++] = i;
    }
}

// ---------------- gather selected patches into bf16 (B*144, 768) ------------
__global__ __launch_bounds__(256) void gather_kernel(const float* __restrict__ magno,
                                                     const int* __restrict__ idx,
                                                     __hip_bfloat16* __restrict__ selp)
{
    int bs = blockIdx.x;              // b*144 + s
    int b = bs / KSEL;
    int pi = idx[bs];
    int gy = pi / 24, gx = pi % 24;
    int t = threadIdx.x, py = t >> 4, px = t & 15;
    size_t src = ((size_t)b * 3 * 384 + gy * 16 + py) * 384 + gx * 16 + px;
    __hip_bfloat16* dst = &selp[(size_t)bs * 768];
#pragma unroll
    for (int c = 0; c < 3; ++c)
        dst[c * 256 + t] = __float2bfloat16(magno[src + (size_t)c * 384 * 384]);
}

// ---------------- f32 -> bf16 elementwise (conv_w, already [N][K]) ----------
__global__ __launch_bounds__(256) void convert_bf16_kernel(const float* __restrict__ src,
                                                           __hip_bfloat16* __restrict__ dst,
                                                           int n)
{
    int i = blockIdx.x * 256 + threadIdx.x;
    if (i < n) dst[i] = __float2bfloat16(src[i]);
}

// ---------------- per-layer transpose+convert: src[l][R][C] -> dst[l][C][R] -
__global__ __launch_bounds__(256) void transpose_w_kernel(const float* __restrict__ src,
                                                          __hip_bfloat16* __restrict__ dst,
                                                          int R, int C)
{
    __shared__ float t[32][33];
    size_t lo = (size_t)blockIdx.z * R * C;
    int r0 = blockIdx.y * 32, c0 = blockIdx.x * 32;
    int tx = threadIdx.x & 31, ty = threadIdx.x >> 5;   // 8 rows per pass
#pragma unroll
    for (int i = 0; i < 32; i += 8)
        t[ty + i][tx] = src[lo + (size_t)(r0 + ty + i) * C + c0 + tx];
    __syncthreads();
#pragma unroll
    for (int i = 0; i < 32; i += 8)
        dst[lo + (size_t)(c0 + ty + i) * R + r0 + tx] = __float2bfloat16(t[tx][ty + i]);
}

// ---------------- cls token init --------------------------------------------
__global__ void cls_kernel(const float* __restrict__ cls, const float* __restrict__ pos,
                           float* __restrict__ h)
{
    int b = blockIdx.x, t = threadIdx.x;      // 192 threads
    h[(size_t)b * SEQ * DIM + t] = cls[t] + pos[t];
}

// ---------------- LayerNorm over D=192 -> bf16 out, one wave per token ------
__global__ __launch_bounds__(256) void ln_kernel(const float* __restrict__ x,
                                                 const float* __restrict__ s,
                                                 const float* __restrict__ bia,
                                                 __hip_bfloat16* __restrict__ y, int ntok)
{
    int w = threadIdx.x >> 6, lane = threadIdx.x & 63;
    int tok = blockIdx.x * 4 + w;
    if (tok >= ntok) return;
    const float* xp = &x[(size_t)tok * DIM];
    float x0 = xp[lane], x1 = xp[lane + 64], x2 = xp[lane + 128];
    float sum = x0 + x1 + x2;
    for (int off = 32; off; off >>= 1) sum += __shfl_xor(sum, off);
    float mean = sum * (1.f / 192.f);
    float d0 = x0 - mean, d1 = x1 - mean, d2 = x2 - mean;
    float vs = d0 * d0 + d1 * d1 + d2 * d2;
    for (int off = 32; off; off >>= 1) vs += __shfl_xor(vs, off);
    float rs = rsqrtf(vs * (1.f / 192.f) + 1e-6f);
    __hip_bfloat16* yp = &y[(size_t)tok * DIM];
    yp[lane]       = __float2bfloat16(d0 * rs * s[lane]       + bia[lane]);
    yp[lane + 64]  = __float2bfloat16(d1 * rs * s[lane + 64]  + bia[lane + 64]);
    yp[lane + 128] = __float2bfloat16(d2 * rs * s[lane + 128] + bia[lane + 128]);
}

// ---------------- bf16 MFMA GEMM: C = A(M,K)bf16 @ Wt(N,K)bf16^T + bias -----
// 64x64 tile, BK=64, 4 waves as 2x2 of 32x32 (2x2 16x16x32 frags each).
// LDS XOR-swizzle (8-elem groups by row&7) keeps ds_read_b128 conflict-free.
// MODE 0: f32 store (qkv)   MODE 1: f32 residual +=   MODE 2: gelu -> bf16
// MODE 3: patch embed (pos add, token scatter) -> f32 h
template <int MODE>
__global__ __launch_bounds__(256) void gemm_bf16(const __hip_bfloat16* __restrict__ A,
                                                 const __hip_bfloat16* __restrict__ Wt,
                                                 const float* __restrict__ bias,
                                                 void* __restrict__ Cout,
                                                 int M, int N, int K,
                                                 const int* __restrict__ selidx,
                                                 const float* __restrict__ pos)
{
    __shared__ __align__(16) char As[8192];   // 64 rows x 64 bf16 (swizzled)
    __shared__ __align__(16) char Bs[8192];
    const int tid = threadIdx.x;
    const int lane = tid & 63, wid = tid >> 6;
    const int wr = wid >> 1, wc = wid & 1;
    const int lr = lane & 15, lk = lane >> 4;
    const int m0 = blockIdx.y * 64, n0 = blockIdx.x * 64;
    f32x4 acc[2][2] = {};

    for (int k0 = 0; k0 < K; k0 += 64) {
#pragma unroll
        for (int it = 0; it < 2; ++it) {
            int chunk = it * 256 + tid;          // 0..511
            int r = chunk >> 3, g = chunk & 7;
            int loff = r * 128 + ((g ^ (r & 7)) * 16);
            *reinterpret_cast<uint4*>(As + loff) =
                *reinterpret_cast<const uint4*>(&A[(size_t)(m0 + r) * K + k0 + g * 8]);
            *reinterpret_cast<uint4*>(Bs + loff) =
                *reinterpret_cast<const uint4*>(&Wt[(size_t)(n0 + r) * K + k0 + g * 8]);
        }
        __syncthreads();
#pragma unroll
        for (int kc = 0; kc < 2; ++kc) {
            int g = kc * 4 + lk;                 // 8-elem k-group within row
            bf16x8 af[2], bfr[2];
#pragma unroll
            for (int mi = 0; mi < 2; ++mi) {
                int r = wr * 32 + mi * 16 + lr;
                af[mi] = *reinterpret_cast<const bf16x8*>(As + r * 128 + ((g ^ (r & 7)) * 16));
            }
#pragma unroll
            for (int ni = 0; ni < 2; ++ni) {
                int r = wc * 32 + ni * 16 + lr;
                bfr[ni] = *reinterpret_cast<const bf16x8*>(Bs + r * 128 + ((g ^ (r & 7)) * 16));
            }
#pragma unroll
            for (int mi = 0; mi < 2; ++mi)
#pragma unroll
                for (int ni = 0; ni < 2; ++ni)
                    acc[mi][ni] = __builtin_amdgcn_mfma_f32_16x16x32_bf16(
                        af[mi], bfr[ni], acc[mi][ni], 0, 0, 0);
        }
        __syncthreads();
    }

    // epilogue: lane holds D[row=(lane>>4)*4+j][col=lane&15] per frag
#pragma unroll
    for (int mi = 0; mi < 2; ++mi)
#pragma unroll
    for (int ni = 0; ni < 2; ++ni)
#pragma unroll
    for (int j = 0; j < 4; ++j) {
        int row = m0 + wr * 32 + mi * 16 + (lane >> 4) * 4 + j;
        int col = n0 + wc * 32 + ni * 16 + (lane & 15);
        float v = acc[mi][ni][j] + bias[col];
        if (MODE == 0) {
            ((float*)Cout)[(size_t)row * N + col] = v;
        } else if (MODE == 1) {
            ((float*)Cout)[(size_t)row * N + col] += v;
        } else if (MODE == 2) {
            ((__hip_bfloat16*)Cout)[(size_t)row * N + col] =
                __float2bfloat16(0.5f * v * (1.f + erff(v * 0.70710678118654752f)));
        } else {
            int bb2 = row / KSEL, ss = row % KSEL;
            int pi = selidx[row];
            v += pos[(size_t)(1 + pi) * DIM + col];
            ((float*)Cout)[((size_t)bb2 * SEQ + 1 + ss) * DIM + col] = v;
        }
    }
}

// ---------------- attention v2: block = (b, h, 32-query tile) ---------------
__global__ __launch_bounds__(256) void attn2_kernel(const float* __restrict__ qkv,
                                                    __hip_bfloat16* __restrict__ o)
{
    __shared__ float Qs[64][34];    // Qs[d][q]
    __shared__ float Kt[64][196];   // Kt[d][key], keys >=145 zero
    __shared__ float Ps[SEQ][34];   // Ps[key][q], normalized probs
    const int b = blockIdx.y;
    const int h = blockIdx.x / 5, qt = blockIdx.x % 5;
    const int tid = threadIdx.x;
    const int tx = tid & 15, ty = tid >> 4;
    const size_t base = (size_t)b * SEQ * 576 + h * 64;

    for (int e = tid; e < 32 * 64; e += 256) {
        int q = e >> 6, d = e & 63;
        int tok = qt * 32 + q;
        Qs[d][q] = (tok < SEQ) ? qkv[base + (size_t)tok * 576 + d] : 0.f;
    }
    for (int e = tid; e < 196 * 64; e += 256) {
        int kk = e >> 6, d = e & 63;
        Kt[d][kk] = (kk < SEQ) ? qkv[base + (size_t)kk * 576 + 192 + d] : 0.f;
    }
    __syncthreads();

    float s[2][12] = {};
#pragma unroll 8
    for (int d = 0; d < 64; ++d) {
        float q0 = Qs[d][2 * ty];
        float q1 = Qs[d][2 * ty + 1];
#pragma unroll
        for (int p = 0; p < 3; ++p) {
            float4 kv = *reinterpret_cast<const float4*>(&Kt[d][p * 64 + 4 * tx]);
            s[0][p * 4 + 0] = fmaf(q0, kv.x, s[0][p * 4 + 0]);
            s[0][p * 4 + 1] = fmaf(q0, kv.y, s[0][p * 4 + 1]);
            s[0][p * 4 + 2] = fmaf(q0, kv.z, s[0][p * 4 + 2]);
            s[0][p * 4 + 3] = fmaf(q0, kv.w, s[0][p * 4 + 3]);
            s[1][p * 4 + 0] = fmaf(q1, kv.x, s[1][p * 4 + 0]);
            s[1][p * 4 + 1] = fmaf(q1, kv.y, s[1][p * 4 + 1]);
            s[1][p * 4 + 2] = fmaf(q1, kv.z, s[1][p * 4 + 2]);
            s[1][p * 4 + 3] = fmaf(q1, kv.w, s[1][p * 4 + 3]);
        }
    }

#pragma unroll
    for (int i = 0; i < 2; ++i) {
#pragma unroll
        for (int e = 0; e < 12; ++e) {
            int key = (e >> 2) * 64 + 4 * tx + (e & 3);
            s[i][e] = (key < SEQ) ? s[i][e] * 0.125f : -1e30f;
        }
        float m = -1e30f;
#pragma unroll
        for (int e = 0; e < 12; ++e) m = fmaxf(m, s[i][e]);
        for (int off = 1; off < 16; off <<= 1) m = fmaxf(m, __shfl_xor(m, off));
        float l = 0.f;
#pragma unroll
        for (int e = 0; e < 12; ++e) { s[i][e] = __expf(s[i][e] - m); l += s[i][e]; }
        for (int off = 1; off < 16; off <<= 1) l += __shfl_xor(l, off);
        float inv = 1.f / l;
#pragma unroll
        for (int e = 0; e < 12; ++e) s[i][e] *= inv;
    }

#pragma unroll
    for (int i = 0; i < 2; ++i)
#pragma unroll
        for (int e = 0; e < 12; ++e) {
            int key = (e >> 2) * 64 + 4 * tx + (e & 3);
            if (key < SEQ) Ps[key][2 * ty + i] = s[i][e];
        }
    __syncthreads();

    float acc[2][4] = {};
#pragma unroll 8
    for (int k = 0; k < SEQ; ++k) {
        float4 vv = *reinterpret_cast<const float4*>(&qkv[base + (size_t)k * 576 + 384 + 4 * tx]);
        float p0 = Ps[k][2 * ty];
        float p1 = Ps[k][2 * ty + 1];
        acc[0][0] = fmaf(p0, vv.x, acc[0][0]);
        acc[0][1] = fmaf(p0, vv.y, acc[0][1]);
        acc[0][2] = fmaf(p0, vv.z, acc[0][2]);
        acc[0][3] = fmaf(p0, vv.w, acc[0][3]);
        acc[1][0] = fmaf(p1, vv.x, acc[1][0]);
        acc[1][1] = fmaf(p1, vv.y, acc[1][1]);
        acc[1][2] = fmaf(p1, vv.z, acc[1][2]);
        acc[1][3] = fmaf(p1, vv.w, acc[1][3]);
    }
#pragma unroll
    for (int i = 0; i < 2; ++i) {
        int tok = qt * 32 + 2 * ty + i;
        if (tok < SEQ) {
            __hip_bfloat16 ov[4];
#pragma unroll
            for (int j = 0; j < 4; ++j) ov[j] = __float2bfloat16(acc[i][j]);
            *reinterpret_cast<uint2*>(&o[((size_t)b * SEQ + tok) * DIM + h * 64 + 4 * tx]) =
                *reinterpret_cast<uint2*>(ov);
        }
    }
}

// ---------------- head: final LN of cls + (64,192)@(192,1000) ---------------
__global__ __launch_bounds__(256) void head_kernel(const float* __restrict__ h,
                                                   const float* __restrict__ nfs,
                                                   const float* __restrict__ nfb,
                                                   const float* __restrict__ hw,
                                                   const float* __restrict__ hb,
                                                   float* __restrict__ out)
{
    int b = blockIdx.x, t = threadIdx.x;
    __shared__ float y[DIM];
    __shared__ float red[4];
    float x = (t < DIM) ? h[(size_t)b * SEQ * DIM + t] : 0.f;
    float sum = x;
    for (int off = 32; off; off >>= 1) sum += __shfl_xor(sum, off);
    if ((t & 63) == 0) red[t >> 6] = sum;
    __syncthreads();
    float mean = (red[0] + red[1] + red[2] + red[3]) * (1.f / 192.f);
    __syncthreads();
    float d = (t < DIM) ? (x - mean) : 0.f;
    float v = d * d;
    for (int off = 32; off; off >>= 1) v += __shfl_xor(v, off);
    if ((t & 63) == 0) red[t >> 6] = v;
    __syncthreads();
    float var = (red[0] + red[1] + red[2] + red[3]) * (1.f / 192.f);
    float rs = rsqrtf(var + 1e-6f);
    if (t < DIM) y[t] = d * rs * nfs[t] + nfb[t];
    __syncthreads();
    for (int n = t; n < 1000; n += 256) {
        float acc = hb[n];
#pragma unroll 8
        for (int k = 0; k < DIM; ++k)
            acc = fmaf(y[k], hw[(size_t)k * 1000 + n], acc);
        out[(size_t)b * 1000 + n] = acc;
    }
}

// ---------------------------------------------------------------------------
extern "C" void kernel_launch(void* const* d_in, const int* in_sizes, int n_in,
                              void* d_out, int out_size, void* d_ws, size_t ws_size,
                              hipStream_t stream)
{
    const float* magno  = (const float*)d_in[0];
    const float* line   = (const float*)d_in[1];
    const float* conv_w = (const float*)d_in[2];
    const float* conv_b = (const float*)d_in[3];
    const float* pos    = (const float*)d_in[4];
    const float* cls    = (const float*)d_in[5];
    const float* ln1_s  = (const float*)d_in[6];
    const float* ln1_b  = (const float*)d_in[7];
    const float* qkv_w  = (const float*)d_in[8];
    const float* qkv_b  = (const float*)d_in[9];
    const float* proj_w = (const float*)d_in[10];
    const float* proj_b = (const float*)d_in[11];
    const float* ln2_s  = (const float*)d_in[12];
    const float* ln2_b  = (const float*)d_in[13];
    const float* fc1_w  = (const float*)d_in[14];
    const float* fc1_b  = (const float*)d_in[15];
    const float* fc2_w  = (const float*)d_in[16];
    const float* fc2_b  = (const float*)d_in[17];
    const float* normf_s = (const float*)d_in[18];
    const float* normf_b = (const float*)d_in[19];
    const float* head_w = (const float*)d_in[20];
    const float* head_b = (const float*)d_in[21];
    float* out = (float*)d_out;
    (void)in_sizes; (void)n_in; (void)out_size; (void)ws_size;

    // workspace layout (bytes), total ~57.1 MB
    char* ws = (char*)d_ws;
    int*            idx     = (int*)            (ws + 0);         //   147456
    float*          h       = (float*)          (ws + 147456);    //  7127040
    __hip_bfloat16* y       = (__hip_bfloat16*) (ws + 7274496);   //  3563520
    float*          qkv     = (float*)          (ws + 10838016);  // 21381120
    __hip_bfloat16* tbuf    = (__hip_bfloat16*) (ws + 32219136);  // 14254080
    __hip_bfloat16* wt_qkv  = (__hip_bfloat16*) (ws + 46473216);  //  2654208
    __hip_bfloat16* wt_proj = (__hip_bfloat16*) (ws + 49127424);  //   884736
    __hip_bfloat16* wt_fc1  = (__hip_bfloat16*) (ws + 50012160);  //  3538944
    __hip_bfloat16* wt_fc2  = (__hip_bfloat16*) (ws + 53551104);  //  3538944
    float*          scoresbuf = qkv;                    // alias (used before qkv)
    __hip_bfloat16* convT     = (__hip_bfloat16*)y;     // alias (used before y)
    __hip_bfloat16* selp      = tbuf;                   // alias (used before tbuf)

    // ---- prep: weights -> bf16 [N][K] ----
    transpose_w_kernel<<<dim3(18, 6, 12), 256, 0, stream>>>(qkv_w, wt_qkv, DIM, 576);
    transpose_w_kernel<<<dim3(6, 6, 12),  256, 0, stream>>>(proj_w, wt_proj, DIM, DIM);
    transpose_w_kernel<<<dim3(24, 6, 12), 256, 0, stream>>>(fc1_w, wt_fc1, DIM, HIDN);
    transpose_w_kernel<<<dim3(6, 24, 12), 256, 0, stream>>>(fc2_w, wt_fc2, HIDN, DIM);
    convert_bf16_kernel<<<576, 256, 0, stream>>>(conv_w, convT, DIM * 768);

    // ---- patch selection + embed ----
    scores_kernel<<<Bsz * NPATCH, 256, 0, stream>>>(line, scoresbuf);
    topk_kernel<<<Bsz, 256, 0, stream>>>(scoresbuf, idx);
    gather_kernel<<<Bsz * KSEL, 256, 0, stream>>>(magno, idx, selp);
    cls_kernel<<<Bsz, DIM, 0, stream>>>(cls, pos, h);
    gemm_bf16<3><<<dim3(3, 144), 256, 0, stream>>>(selp, convT, conv_b, h,
                                                   9216, DIM, 768, idx, pos);

    const int ntok = Bsz * SEQ;              // 9280 = 145*64
    for (int l = 0; l < 12; ++l) {
        ln_kernel<<<ntok / 4, 256, 0, stream>>>(h, ln1_s + l * DIM, ln1_b + l * DIM, y, ntok);
        gemm_bf16<0><<<dim3(9, 145), 256, 0, stream>>>(y, wt_qkv + (size_t)l * 576 * DIM,
                                                       qkv_b + l * 576, qkv,
                                                       ntok, 576, DIM, nullptr, nullptr);
        attn2_kernel<<<dim3(15, Bsz), 256, 0, stream>>>(qkv, y);
        gemm_bf16<1><<<dim3(3, 145), 256, 0, stream>>>(y, wt_proj + (size_t)l * DIM * DIM,
                                                       proj_b + l * DIM, h,
                                                       ntok, DIM, DIM, nullptr, nullptr);
        ln_kernel<<<ntok / 4, 256, 0, stream>>>(h, ln2_s + l * DIM, ln2_b + l * DIM, y, ntok);
        gemm_bf16<2><<<dim3(12, 145), 256, 0, stream>>>(y, wt_fc1 + (size_t)l * HIDN * DIM,
                                                        fc1_b + l * HIDN, tbuf,
                                                        ntok, HIDN, DIM, nullptr, nullptr);
        gemm_bf16<1><<<dim3(3, 145), 256, 0, stream>>>(tbuf, wt_fc2 + (size_t)l * DIM * HIDN,
                                                       fc2_b + l * DIM, h,
                                                       ntok, DIM, HIDN, nullptr, nullptr);
    }
    head_kernel<<<Bsz, 256, 0, stream>>>(h, normf_s, normf_b, head_w, head_b, out);
}

// Round 4
// 1004.752 us; speedup vs baseline: 4.7684x; 1.6201x over previous
//
#include <hip/hip_runtime.h>
#include <hip/hip_bf16.h>
#include <cmath>

// ---------------------------------------------------------------------------
// SelectiveMagnoViT forward. Round 3: MFMA attention (bf16 qkv, Vt transpose,
// 2-wave blocks, in-register softmax). GEMMs bf16 MFMA as round 2.
// ---------------------------------------------------------------------------

#define Bsz   64
#define NPATCH 576
#define KSEL  144
#define SEQ   145
#define DIM   192
#define HIDN  768

typedef __bf16 bf16x8 __attribute__((ext_vector_type(8)));
typedef float  f32x4  __attribute__((ext_vector_type(4)));

// ---------------- patch scores: 16x16 average pool of line drawing ----------
__global__ __launch_bounds__(256) void scores_kernel(const float* __restrict__ line,
                                                     float* __restrict__ scores)
{
    int gp = blockIdx.x;              // b*576 + p
    int b = gp / NPATCH, p = gp % NPATCH;
    int gy = p / 24, gx = p % 24;
    int t = threadIdx.x, py = t >> 4, px = t & 15;
    float v = line[((size_t)b * 384 + gy * 16 + py) * 384 + gx * 16 + px];
    for (int off = 32; off; off >>= 1) v += __shfl_xor(v, off);
    __shared__ float red[4];
    if ((t & 63) == 0) red[t >> 6] = v;
    __syncthreads();
    if (t == 0) scores[gp] = (red[0] + red[1] + red[2] + red[3]) * (1.f / 256.f);
}

// ---------------- exact top-k (set semantics; jax tie-break: lower idx wins) -
__global__ __launch_bounds__(256) void topk_kernel(const float* __restrict__ scores,
                                                   int* __restrict__ idx)
{
    int b = blockIdx.x;
    __shared__ float s[NPATCH];
    __shared__ unsigned char sel[NPATCH];
    for (int i = threadIdx.x; i < NPATCH; i += 256) s[i] = scores[b * NPATCH + i];
    __syncthreads();
    for (int i = threadIdx.x; i < NPATCH; i += 256) {
        float si = s[i];
        int cnt = 0;
        for (int j = 0; j < NPATCH; ++j) {
            float sj = s[j];
            cnt += (sj > si) || (sj == si && j < i);
        }
        sel[i] = (cnt < KSEL) ? 1 : 0;
    }
    __syncthreads();
    if (threadIdx.x == 0) {
        int slot = 0;
        for (int i = 0; i < NPATCH; ++i)
            if (sel[i]) idx[b * KSEL + slot++] = i;
    }
}

// ---------------- gather selected patches into bf16 (B*144, 768) ------------
__global__ __launch_bounds__(256) void gather_kernel(const float* __restrict__ magno,
                                                     const int* __restrict__ idx,
                                                     __hip_bfloat16* __restrict__ selp)
{
    int bs = blockIdx.x;              // b*144 + s
    int b = bs / KSEL;
    int pi = idx[bs];
    int gy = pi / 24, gx = pi % 24;
    int t = threadIdx.x, py = t >> 4, px = t & 15;
    size_t src = ((size_t)b * 3 * 384 + gy * 16 + py) * 384 + gx * 16 + px;
    __hip_bfloat16* dst = &selp[(size_t)bs * 768];
#pragma unroll
    for (int c = 0; c < 3; ++c)
        dst[c * 256 + t] = __float2bfloat16(magno[src + (size_t)c * 384 * 384]);
}

// ---------------- f32 -> bf16 elementwise (conv_w, already [N][K]) ----------
__global__ __launch_bounds__(256) void convert_bf16_kernel(const float* __restrict__ src,
                                                           __hip_bfloat16* __restrict__ dst,
                                                           int n)
{
    int i = blockIdx.x * 256 + threadIdx.x;
    if (i < n) dst[i] = __float2bfloat16(src[i]);
}

// ---------------- per-layer transpose+convert: src[l][R][C] -> dst[l][C][R] -
__global__ __launch_bounds__(256) void transpose_w_kernel(const float* __restrict__ src,
                                                          __hip_bfloat16* __restrict__ dst,
                                                          int R, int C)
{
    __shared__ float t[32][33];
    size_t lo = (size_t)blockIdx.z * R * C;
    int r0 = blockIdx.y * 32, c0 = blockIdx.x * 32;
    int tx = threadIdx.x & 31, ty = threadIdx.x >> 5;   // 8 rows per pass
#pragma unroll
    for (int i = 0; i < 32; i += 8)
        t[ty + i][tx] = src[lo + (size_t)(r0 + ty + i) * C + c0 + tx];
    __syncthreads();
#pragma unroll
    for (int i = 0; i < 32; i += 8)
        dst[lo + (size_t)(c0 + ty + i) * R + r0 + tx] = __float2bfloat16(t[tx][ty + i]);
}

// ---------------- cls token init --------------------------------------------
__global__ void cls_kernel(const float* __restrict__ cls, const float* __restrict__ pos,
                           float* __restrict__ h)
{
    int b = blockIdx.x, t = threadIdx.x;      // 192 threads
    h[(size_t)b * SEQ * DIM + t] = cls[t] + pos[t];
}

// ---------------- LayerNorm over D=192 -> bf16 out, one wave per token ------
__global__ __launch_bounds__(256) void ln_kernel(const float* __restrict__ x,
                                                 const float* __restrict__ s,
                                                 const float* __restrict__ bia,
                                                 __hip_bfloat16* __restrict__ y, int ntok)
{
    int w = threadIdx.x >> 6, lane = threadIdx.x & 63;
    int tok = blockIdx.x * 4 + w;
    if (tok >= ntok) return;
    const float* xp = &x[(size_t)tok * DIM];
    float x0 = xp[lane], x1 = xp[lane + 64], x2 = xp[lane + 128];
    float sum = x0 + x1 + x2;
    for (int off = 32; off; off >>= 1) sum += __shfl_xor(sum, off);
    float mean = sum * (1.f / 192.f);
    float d0 = x0 - mean, d1 = x1 - mean, d2 = x2 - mean;
    float vs = d0 * d0 + d1 * d1 + d2 * d2;
    for (int off = 32; off; off >>= 1) vs += __shfl_xor(vs, off);
    float rs = rsqrtf(vs * (1.f / 192.f) + 1e-6f);
    __hip_bfloat16* yp = &y[(size_t)tok * DIM];
    yp[lane]       = __float2bfloat16(d0 * rs * s[lane]       + bia[lane]);
    yp[lane + 64]  = __float2bfloat16(d1 * rs * s[lane + 64]  + bia[lane + 64]);
    yp[lane + 128] = __float2bfloat16(d2 * rs * s[lane + 128] + bia[lane + 128]);
}

// ---------------- bf16 MFMA GEMM: C = A(M,K)bf16 @ Wt(N,K)bf16^T + bias -----
// MODE 0: bf16 store (qkv)  MODE 1: f32 residual +=  MODE 2: gelu -> bf16
// MODE 3: patch embed (pos add, token scatter) -> f32 h
template <int MODE>
__global__ __launch_bounds__(256) void gemm_bf16(const __hip_bfloat16* __restrict__ A,
                                                 const __hip_bfloat16* __restrict__ Wt,
                                                 const float* __restrict__ bias,
                                                 void* __restrict__ Cout,
                                                 int M, int N, int K,
                                                 const int* __restrict__ selidx,
                                                 const float* __restrict__ pos)
{
    __shared__ __align__(16) char As[8192];   // 64 rows x 64 bf16 (swizzled)
    __shared__ __align__(16) char Bs[8192];
    const int tid = threadIdx.x;
    const int lane = tid & 63, wid = tid >> 6;
    const int wr = wid >> 1, wc = wid & 1;
    const int lr = lane & 15, lk = lane >> 4;
    const int m0 = blockIdx.y * 64, n0 = blockIdx.x * 64;
    f32x4 acc[2][2] = {};

    for (int k0 = 0; k0 < K; k0 += 64) {
#pragma unroll
        for (int it = 0; it < 2; ++it) {
            int chunk = it * 256 + tid;          // 0..511
            int r = chunk >> 3, g = chunk & 7;
            int loff = r * 128 + ((g ^ (r & 7)) * 16);
            *reinterpret_cast<uint4*>(As + loff) =
                *reinterpret_cast<const uint4*>(&A[(size_t)(m0 + r) * K + k0 + g * 8]);
            *reinterpret_cast<uint4*>(Bs + loff) =
                *reinterpret_cast<const uint4*>(&Wt[(size_t)(n0 + r) * K + k0 + g * 8]);
        }
        __syncthreads();
#pragma unroll
        for (int kc = 0; kc < 2; ++kc) {
            int g = kc * 4 + lk;                 // 8-elem k-group within row
            bf16x8 af[2], bfr[2];
#pragma unroll
            for (int mi = 0; mi < 2; ++mi) {
                int r = wr * 32 + mi * 16 + lr;
                af[mi] = *reinterpret_cast<const bf16x8*>(As + r * 128 + ((g ^ (r & 7)) * 16));
            }
#pragma unroll
            for (int ni = 0; ni < 2; ++ni) {
                int r = wc * 32 + ni * 16 + lr;
                bfr[ni] = *reinterpret_cast<const bf16x8*>(Bs + r * 128 + ((g ^ (r & 7)) * 16));
            }
#pragma unroll
            for (int mi = 0; mi < 2; ++mi)
#pragma unroll
                for (int ni = 0; ni < 2; ++ni)
                    acc[mi][ni] = __builtin_amdgcn_mfma_f32_16x16x32_bf16(
                        af[mi], bfr[ni], acc[mi][ni], 0, 0, 0);
        }
        __syncthreads();
    }

    // epilogue: lane holds D[row=(lane>>4)*4+j][col=lane&15] per frag
#pragma unroll
    for (int mi = 0; mi < 2; ++mi)
#pragma unroll
    for (int ni = 0; ni < 2; ++ni)
#pragma unroll
    for (int j = 0; j < 4; ++j) {
        int row = m0 + wr * 32 + mi * 16 + (lane >> 4) * 4 + j;
        int col = n0 + wc * 32 + ni * 16 + (lane & 15);
        float v = acc[mi][ni][j] + bias[col];
        if (MODE == 0) {
            ((__hip_bfloat16*)Cout)[(size_t)row * N + col] = __float2bfloat16(v);
        } else if (MODE == 1) {
            ((float*)Cout)[(size_t)row * N + col] += v;
        } else if (MODE == 2) {
            ((__hip_bfloat16*)Cout)[(size_t)row * N + col] =
                __float2bfloat16(0.5f * v * (1.f + erff(v * 0.70710678118654752f)));
        } else {
            int bb2 = row / KSEL, ss = row % KSEL;
            int pi = selidx[row];
            v += pos[(size_t)(1 + pi) * DIM + col];
            ((float*)Cout)[((size_t)bb2 * SEQ + 1 + ss) * DIM + col] = v;
        }
    }
}

// ---------------- V transpose: qkv[b][s][384+h*64+d] -> Vt[(b*3+h)][d][s] ---
// Keys padded to 160 with zeros.
__global__ __launch_bounds__(256) void vtrans_kernel(const __hip_bfloat16* __restrict__ qkv,
                                                     __hip_bfloat16* __restrict__ Vt)
{
    const int b = blockIdx.x, h = blockIdx.y;
    __shared__ unsigned short lds[160][72];
    const int tid = threadIdx.x;
    for (int c = tid; c < 160 * 8; c += 256) {
        int s = c >> 3, g = c & 7;
        uint4 v = make_uint4(0, 0, 0, 0);
        if (s < SEQ)
            v = *reinterpret_cast<const uint4*>(
                &qkv[((size_t)b * SEQ + s) * 576 + 384 + h * 64 + g * 8]);
        *reinterpret_cast<uint4*>(&lds[s][g * 8]) = v;
    }
    __syncthreads();
    unsigned short* dst = (unsigned short*)&Vt[(size_t)(b * 3 + h) * 64 * 160];
    for (int e = tid; e < 64 * 160; e += 256) {
        int d = e / 160, s = e - d * 160;
        dst[e] = lds[s][d];
    }
}

// ---------------- attention v3: MFMA, block=(b,h,qtile of 32), 2 waves ------
// Wave handles 16 query rows. QK^T: A=Q frags from global, B=K frags from
// global (keys padded to 160, masked post-MFMA). Softmax in-register on the
// C layout (col=lane&15, row=(lane>>4)*4+j), row-reduce via shfl_xor over the
// 16 col-lanes. P -> bf16 LDS [16][168] per wave, PV: A from LDS, B from Vt.
__global__ __launch_bounds__(128) void attn3_kernel(const __hip_bfloat16* __restrict__ qkv,
                                                    const __hip_bfloat16* __restrict__ Vt,
                                                    __hip_bfloat16* __restrict__ o)
{
    const int b = blockIdx.y;
    const int h = blockIdx.x / 5, qt = blockIdx.x % 5;
    const int tid = threadIdx.x;
    const int wq = tid >> 6, lane = tid & 63;
    const int lr = lane & 15, lg = lane >> 4;
    __shared__ __hip_bfloat16 Ps[2][16][168];

    const size_t qbase = (size_t)b * SEQ * 576;
    const int q0 = qt * 32 + wq * 16;

    // Q A-frags: lane reads Q[q0+lr][ks*32+lg*8 .. +8]  (rows>=SEQ: garbage ok)
    bf16x8 aq[2];
#pragma unroll
    for (int ks = 0; ks < 2; ++ks)
        aq[ks] = *reinterpret_cast<const bf16x8*>(
            &qkv[qbase + (size_t)(q0 + lr) * 576 + h * 64 + ks * 32 + lg * 8]);

    // QK^T: 10 n-frags of 16 keys
    f32x4 sc[10];
#pragma unroll
    for (int nf = 0; nf < 10; ++nf) sc[nf] = (f32x4){0.f, 0.f, 0.f, 0.f};
#pragma unroll
    for (int nf = 0; nf < 10; ++nf) {
        int key = nf * 16 + lr;
#pragma unroll
        for (int ks = 0; ks < 2; ++ks) {
            bf16x8 bk = *reinterpret_cast<const bf16x8*>(
                &qkv[qbase + (size_t)key * 576 + 192 + h * 64 + ks * 32 + lg * 8]);
            sc[nf] = __builtin_amdgcn_mfma_f32_16x16x32_bf16(aq[ks], bk, sc[nf], 0, 0, 0);
        }
    }

    // softmax (rows = lg*4+j, cols spread over 16 lanes x 10 frags)
    float mx[4] = {-1e30f, -1e30f, -1e30f, -1e30f};
#pragma unroll
    for (int nf = 0; nf < 10; ++nf) {
        bool valid = nf * 16 + lr < SEQ;
#pragma unroll
        for (int j = 0; j < 4; ++j) {
            float v = valid ? sc[nf][j] * 0.125f : -1e30f;
            sc[nf][j] = v;
            mx[j] = fmaxf(mx[j], v);
        }
    }
#pragma unroll
    for (int j = 0; j < 4; ++j)
        for (int off = 1; off < 16; off <<= 1)
            mx[j] = fmaxf(mx[j], __shfl_xor(mx[j], off));
    float sm[4] = {0.f, 0.f, 0.f, 0.f};
#pragma unroll
    for (int nf = 0; nf < 10; ++nf)
#pragma unroll
        for (int j = 0; j < 4; ++j) {
            float p = __expf(sc[nf][j] - mx[j]);
            sc[nf][j] = p;
            sm[j] += p;
        }
#pragma unroll
    for (int j = 0; j < 4; ++j) {
        for (int off = 1; off < 16; off <<= 1) sm[j] += __shfl_xor(sm[j], off);
        sm[j] = 1.f / sm[j];
    }
#pragma unroll
    for (int nf = 0; nf < 10; ++nf) {
        int key = nf * 16 + lr;
#pragma unroll
        for (int j = 0; j < 4; ++j)
            Ps[wq][lg * 4 + j][key] = __float2bfloat16(sc[nf][j] * sm[j]);
    }
    __syncthreads();

    // PV: A = P from LDS, B = V from Vt (zero-padded keys)
    const __hip_bfloat16* vtb = &Vt[(size_t)(b * 3 + h) * 64 * 160];
    f32x4 oacc[4];
#pragma unroll
    for (int nf = 0; nf < 4; ++nf) oacc[nf] = (f32x4){0.f, 0.f, 0.f, 0.f};
#pragma unroll
    for (int ks = 0; ks < 5; ++ks) {
        bf16x8 ap = *reinterpret_cast<const bf16x8*>(&Ps[wq][lr][ks * 32 + lg * 8]);
#pragma unroll
        for (int nf = 0; nf < 4; ++nf) {
            bf16x8 bv = *reinterpret_cast<const bf16x8*>(
                &vtb[(size_t)(nf * 16 + lr) * 160 + ks * 32 + lg * 8]);
            oacc[nf] = __builtin_amdgcn_mfma_f32_16x16x32_bf16(ap, bv, oacc[nf], 0, 0, 0);
        }
    }
#pragma unroll
    for (int nf = 0; nf < 4; ++nf)
#pragma unroll
        for (int j = 0; j < 4; ++j) {
            int q = q0 + lg * 4 + j;
            if (q < SEQ)
                o[((size_t)b * SEQ + q) * DIM + h * 64 + nf * 16 + lr] =
                    __float2bfloat16(oacc[nf][j]);
        }
}

// ---------------- head: final LN of cls + (64,192)@(192,1000) ---------------
__global__ __launch_bounds__(256) void head_kernel(const float* __restrict__ h,
                                                   const float* __restrict__ nfs,
                                                   const float* __restrict__ nfb,
                                                   const float* __restrict__ hw,
                                                   const float* __restrict__ hb,
                                                   float* __restrict__ out)
{
    int b = blockIdx.x, t = threadIdx.x;
    __shared__ float y[DIM];
    __shared__ float red[4];
    float x = (t < DIM) ? h[(size_t)b * SEQ * DIM + t] : 0.f;
    float sum = x;
    for (int off = 32; off; off >>= 1) sum += __shfl_xor(sum, off);
    if ((t & 63) == 0) red[t >> 6] = sum;
    __syncthreads();
    float mean = (red[0] + red[1] + red[2] + red[3]) * (1.f / 192.f);
    __syncthreads();
    float d = (t < DIM) ? (x - mean) : 0.f;
    float v = d * d;
    for (int off = 32; off; off >>= 1) v += __shfl_xor(v, off);
    if ((t & 63) == 0) red[t >> 6] = v;
    __syncthreads();
    float var = (red[0] + red[1] + red[2] + red[3]) * (1.f / 192.f);
    float rs = rsqrtf(var + 1e-6f);
    if (t < DIM) y[t] = d * rs * nfs[t] + nfb[t];
    __syncthreads();
    for (int n = t; n < 1000; n += 256) {
        float acc = hb[n];
#pragma unroll 8
        for (int k = 0; k < DIM; ++k)
            acc = fmaf(y[k], hw[(size_t)k * 1000 + n], acc);
        out[(size_t)b * 1000 + n] = acc;
    }
}

// ---------------------------------------------------------------------------
extern "C" void kernel_launch(void* const* d_in, const int* in_sizes, int n_in,
                              void* d_out, int out_size, void* d_ws, size_t ws_size,
                              hipStream_t stream)
{
    const float* magno  = (const float*)d_in[0];
    const float* line   = (const float*)d_in[1];
    const float* conv_w = (const float*)d_in[2];
    const float* conv_b = (const float*)d_in[3];
    const float* pos    = (const float*)d_in[4];
    const float* cls    = (const float*)d_in[5];
    const float* ln1_s  = (const float*)d_in[6];
    const float* ln1_b  = (const float*)d_in[7];
    const float* qkv_w  = (const float*)d_in[8];
    const float* qkv_b  = (const float*)d_in[9];
    const float* proj_w = (const float*)d_in[10];
    const float* proj_b = (const float*)d_in[11];
    const float* ln2_s  = (const float*)d_in[12];
    const float* ln2_b  = (const float*)d_in[13];
    const float* fc1_w  = (const float*)d_in[14];
    const float* fc1_b  = (const float*)d_in[15];
    const float* fc2_w  = (const float*)d_in[16];
    const float* fc2_b  = (const float*)d_in[17];
    const float* normf_s = (const float*)d_in[18];
    const float* normf_b = (const float*)d_in[19];
    const float* head_w = (const float*)d_in[20];
    const float* head_b = (const float*)d_in[21];
    float* out = (float*)d_out;
    (void)in_sizes; (void)n_in; (void)out_size; (void)ws_size;

    // workspace layout (bytes), total ~50.3 MB
    char* ws = (char*)d_ws;
    int*            idx     = (int*)            (ws + 0);         //   147456
    float*          h       = (float*)          (ws + 147456);    //  7127040
    __hip_bfloat16* y       = (__hip_bfloat16*) (ws + 7274496);   //  3563520
    __hip_bfloat16* qkv     = (__hip_bfloat16*) (ws + 10838016);  // 10690560
    __hip_bfloat16* Vt      = (__hip_bfloat16*) (ws + 21528576);  //  3932160
    __hip_bfloat16* tbuf    = (__hip_bfloat16*) (ws + 25460736);  // 14254080
    __hip_bfloat16* wt_qkv  = (__hip_bfloat16*) (ws + 39714816);  //  2654208
    __hip_bfloat16* wt_proj = (__hip_bfloat16*) (ws + 42369024);  //   884736
    __hip_bfloat16* wt_fc1  = (__hip_bfloat16*) (ws + 43253760);  //  3538944
    __hip_bfloat16* wt_fc2  = (__hip_bfloat16*) (ws + 46792704);  //  3538944
    float*          scoresbuf = (float*)qkv;            // alias (used before qkv)
    __hip_bfloat16* convT     = y;                      // alias (used before y)
    __hip_bfloat16* selp      = tbuf;                   // alias (used before tbuf)

    // ---- prep: weights -> bf16 [N][K] ----
    transpose_w_kernel<<<dim3(18, 6, 12), 256, 0, stream>>>(qkv_w, wt_qkv, DIM, 576);
    transpose_w_kernel<<<dim3(6, 6, 12),  256, 0, stream>>>(proj_w, wt_proj, DIM, DIM);
    transpose_w_kernel<<<dim3(24, 6, 12), 256, 0, stream>>>(fc1_w, wt_fc1, DIM, HIDN);
    transpose_w_kernel<<<dim3(6, 24, 12), 256, 0, stream>>>(fc2_w, wt_fc2, HIDN, DIM);
    convert_bf16_kernel<<<576, 256, 0, stream>>>(conv_w, convT, DIM * 768);

    // ---- patch selection + embed ----
    scores_kernel<<<Bsz * NPATCH, 256, 0, stream>>>(line, scoresbuf);
    topk_kernel<<<Bsz, 256, 0, stream>>>(scoresbuf, idx);
    gather_kernel<<<Bsz * KSEL, 256, 0, stream>>>(magno, idx, selp);
    cls_kernel<<<Bsz, DIM, 0, stream>>>(cls, pos, h);
    gemm_bf16<3><<<dim3(3, 144), 256, 0, stream>>>(selp, convT, conv_b, h,
                                                   9216, DIM, 768, idx, pos);

    const int ntok = Bsz * SEQ;              // 9280 = 145*64
    for (int l = 0; l < 12; ++l) {
        ln_kernel<<<ntok / 4, 256, 0, stream>>>(h, ln1_s + l * DIM, ln1_b + l * DIM, y, ntok);
        gemm_bf16<0><<<dim3(9, 145), 256, 0, stream>>>(y, wt_qkv + (size_t)l * 576 * DIM,
                                                       qkv_b + l * 576, qkv,
                                                       ntok, 576, DIM, nullptr, nullptr);
        vtrans_kernel<<<dim3(Bsz, 3), 256, 0, stream>>>(qkv, Vt);
        attn3_kernel<<<dim3(15, Bsz), 128, 0, stream>>>(qkv, Vt, y);
        gemm_bf16<1><<<dim3(3, 145), 256, 0, stream>>>(y, wt_proj + (size_t)l * DIM * DIM,
                                                       proj_b + l * DIM, h,
                                                       ntok, DIM, DIM, nullptr, nullptr);
        ln_kernel<<<ntok / 4, 256, 0, stream>>>(h, ln2_s + l * DIM, ln2_b + l * DIM, y, ntok);
        gemm_bf16<2><<<dim3(12, 145), 256, 0, stream>>>(y, wt_fc1 + (size_t)l * HIDN * DIM,
                                                        fc1_b + l * HIDN, tbuf,
                                                        ntok, HIDN, DIM, nullptr, nullptr);
        gemm_bf16<1><<<dim3(3, 145), 256, 0, stream>>>(tbuf, wt_fc2 + (size_t)l * DIM * HIDN,
                                                       fc2_b + l * DIM, h,
                                                       ntok, DIM, HIDN, nullptr, nullptr);
    }
    head_kernel<<<Bsz, 256, 0, stream>>>(h, normf_s, normf_b, head_w, head_b, out);
}

// Round 5
// 969.930 us; speedup vs baseline: 4.9395x; 1.0359x over previous
//
#include <hip/hip_runtime.h>
#include <hip/hip_bf16.h>
#include <cmath>

// ---------------------------------------------------------------------------
// SelectiveMagnoViT forward. Round 4: rank-scatter topk (no serial scan),
// V^T produced directly by a transposed-epilogue GEMM (vtrans removed),
// proj and fc2 GEMMs fused with bias+residual+LayerNorm (full-row blocks).
// ---------------------------------------------------------------------------

#define Bsz   64
#define NPATCH 576
#define KSEL  144
#define SEQ   145
#define DIM   192
#define HIDN  768

typedef __bf16 bf16x8 __attribute__((ext_vector_type(8)));
typedef float  f32x4  __attribute__((ext_vector_type(4)));

// ---------------- patch scores: 16x16 average pool of line drawing ----------
__global__ __launch_bounds__(256) void scores_kernel(const float* __restrict__ line,
                                                     float* __restrict__ scores)
{
    int gp = blockIdx.x;              // b*576 + p
    int b = gp / NPATCH, p = gp % NPATCH;
    int gy = p / 24, gx = p % 24;
    int t = threadIdx.x, py = t >> 4, px = t & 15;
    float v = line[((size_t)b * 384 + gy * 16 + py) * 384 + gx * 16 + px];
    for (int off = 32; off; off >>= 1) v += __shfl_xor(v, off);
    __shared__ float red[4];
    if ((t & 63) == 0) red[t >> 6] = v;
    __syncthreads();
    if (t == 0) scores[gp] = (red[0] + red[1] + red[2] + red[3]) * (1.f / 256.f);
}

// ---------------- exact top-k via rank scatter (jax order, no serial) -------
__global__ __launch_bounds__(256) void topk_kernel(const float* __restrict__ scores,
                                                   int* __restrict__ idx)
{
    int b = blockIdx.x;
    __shared__ float s[NPATCH];
    for (int i = threadIdx.x; i < NPATCH; i += 256) s[i] = scores[b * NPATCH + i];
    __syncthreads();
    for (int i = threadIdx.x; i < NPATCH; i += 256) {
        float si = s[i];
        int cnt = 0;
        for (int j = 0; j < NPATCH; ++j) {
            float sj = s[j];
            cnt += (sj > si) || (sj == si && j < i);
        }
        // rank is a bijection (strict total order w/ tie-break) -> direct slot
        if (cnt < KSEL) idx[b * KSEL + cnt] = i;
    }
}

// ---------------- gather selected patches into bf16 (B*144, 768) ------------
__global__ __launch_bounds__(256) void gather_kernel(const float* __restrict__ magno,
                                                     const int* __restrict__ idx,
                                                     __hip_bfloat16* __restrict__ selp)
{
    int bs = blockIdx.x;              // b*144 + s
    int b = bs / KSEL;
    int pi = idx[bs];
    int gy = pi / 24, gx = pi % 24;
    int t = threadIdx.x, py = t >> 4, px = t & 15;
    size_t src = ((size_t)b * 3 * 384 + gy * 16 + py) * 384 + gx * 16 + px;
    __hip_bfloat16* dst = &selp[(size_t)bs * 768];
#pragma unroll
    for (int c = 0; c < 3; ++c)
        dst[c * 256 + t] = __float2bfloat16(magno[src + (size_t)c * 384 * 384]);
}

// ---------------- f32 -> bf16 elementwise (conv_w, already [N][K]) ----------
__global__ __launch_bounds__(256) void convert_bf16_kernel(const float* __restrict__ src,
                                                           __hip_bfloat16* __restrict__ dst,
                                                           int n)
{
    int i = blockIdx.x * 256 + threadIdx.x;
    if (i < n) dst[i] = __float2bfloat16(src[i]);
}

// ---------------- per-layer transpose+convert: src[l][R][C] -> dst[l][C][R] -
__global__ __launch_bounds__(256) void transpose_w_kernel(const float* __restrict__ src,
                                                          __hip_bfloat16* __restrict__ dst,
                                                          int R, int C)
{
    __shared__ float t[32][33];
    size_t lo = (size_t)blockIdx.z * R * C;
    int r0 = blockIdx.y * 32, c0 = blockIdx.x * 32;
    int tx = threadIdx.x & 31, ty = threadIdx.x >> 5;   // 8 rows per pass
#pragma unroll
    for (int i = 0; i < 32; i += 8)
        t[ty + i][tx] = src[lo + (size_t)(r0 + ty + i) * C + c0 + tx];
    __syncthreads();
#pragma unroll
    for (int i = 0; i < 32; i += 8)
        dst[lo + (size_t)(c0 + ty + i) * R + r0 + tx] = __float2bfloat16(t[tx][ty + i]);
}

// ---------------- cls token init --------------------------------------------
__global__ void cls_kernel(const float* __restrict__ cls, const float* __restrict__ pos,
                           float* __restrict__ h)
{
    int b = blockIdx.x, t = threadIdx.x;      // 192 threads
    h[(size_t)b * SEQ * DIM + t] = cls[t] + pos[t];
}

// ---------------- LayerNorm over D=192 -> bf16 out (layer-0 ln1 only) -------
__global__ __launch_bounds__(256) void ln_kernel(const float* __restrict__ x,
                                                 const float* __restrict__ s,
                                                 const float* __restrict__ bia,
                                                 __hip_bfloat16* __restrict__ y, int ntok)
{
    int w = threadIdx.x >> 6, lane = threadIdx.x & 63;
    int tok = blockIdx.x * 4 + w;
    if (tok >= ntok) return;
    const float* xp = &x[(size_t)tok * DIM];
    float x0 = xp[lane], x1 = xp[lane + 64], x2 = xp[lane + 128];
    float sum = x0 + x1 + x2;
    for (int off = 32; off; off >>= 1) sum += __shfl_xor(sum, off);
    float mean = sum * (1.f / 192.f);
    float d0 = x0 - mean, d1 = x1 - mean, d2 = x2 - mean;
    float vs = d0 * d0 + d1 * d1 + d2 * d2;
    for (int off = 32; off; off >>= 1) vs += __shfl_xor(vs, off);
    float rs = rsqrtf(vs * (1.f / 192.f) + 1e-6f);
    __hip_bfloat16* yp = &y[(size_t)tok * DIM];
    yp[lane]       = __float2bfloat16(d0 * rs * s[lane]       + bia[lane]);
    yp[lane + 64]  = __float2bfloat16(d1 * rs * s[lane + 64]  + bia[lane + 64]);
    yp[lane + 128] = __float2bfloat16(d2 * rs * s[lane + 128] + bia[lane + 128]);
}

// ---------------- bf16 MFMA GEMM: C = A(M,K)bf16 @ Wt(N,K)bf16^T + bias -----
// MODE 0: bf16 store   MODE 2: gelu -> bf16   MODE 3: patch embed -> f32 h
template <int MODE>
__global__ __launch_bounds__(256) void gemm_bf16(const __hip_bfloat16* __restrict__ A,
                                                 const __hip_bfloat16* __restrict__ Wt,
                                                 const float* __restrict__ bias,
                                                 void* __restrict__ Cout,
                                                 int M, int N, int K,
                                                 const int* __restrict__ selidx,
                                                 const float* __restrict__ pos)
{
    __shared__ __align__(16) char As[8192];   // 64 rows x 64 bf16 (swizzled)
    __shared__ __align__(16) char Bs[8192];
    const int tid = threadIdx.x;
    const int lane = tid & 63, wid = tid >> 6;
    const int wr = wid >> 1, wc = wid & 1;
    const int lr = lane & 15, lk = lane >> 4;
    const int m0 = blockIdx.y * 64, n0 = blockIdx.x * 64;
    f32x4 acc[2][2] = {};

    for (int k0 = 0; k0 < K; k0 += 64) {
#pragma unroll
        for (int it = 0; it < 2; ++it) {
            int chunk = it * 256 + tid;          // 0..511
            int r = chunk >> 3, g = chunk & 7;
            int loff = r * 128 + ((g ^ (r & 7)) * 16);
            *reinterpret_cast<uint4*>(As + loff) =
                *reinterpret_cast<const uint4*>(&A[(size_t)(m0 + r) * K + k0 + g * 8]);
            *reinterpret_cast<uint4*>(Bs + loff) =
                *reinterpret_cast<const uint4*>(&Wt[(size_t)(n0 + r) * K + k0 + g * 8]);
        }
        __syncthreads();
#pragma unroll
        for (int kc = 0; kc < 2; ++kc) {
            int g = kc * 4 + lk;                 // 8-elem k-group within row
            bf16x8 af[2], bfr[2];
#pragma unroll
            for (int mi = 0; mi < 2; ++mi) {
                int r = wr * 32 + mi * 16 + lr;
                af[mi] = *reinterpret_cast<const bf16x8*>(As + r * 128 + ((g ^ (r & 7)) * 16));
            }
#pragma unroll
            for (int ni = 0; ni < 2; ++ni) {
                int r = wc * 32 + ni * 16 + lr;
                bfr[ni] = *reinterpret_cast<const bf16x8*>(Bs + r * 128 + ((g ^ (r & 7)) * 16));
            }
#pragma unroll
            for (int mi = 0; mi < 2; ++mi)
#pragma unroll
                for (int ni = 0; ni < 2; ++ni)
                    acc[mi][ni] = __builtin_amdgcn_mfma_f32_16x16x32_bf16(
                        af[mi], bfr[ni], acc[mi][ni], 0, 0, 0);
        }
        __syncthreads();
    }

#pragma unroll
    for (int mi = 0; mi < 2; ++mi)
#pragma unroll
    for (int ni = 0; ni < 2; ++ni)
#pragma unroll
    for (int j = 0; j < 4; ++j) {
        int row = m0 + wr * 32 + mi * 16 + (lane >> 4) * 4 + j;
        int col = n0 + wc * 32 + ni * 16 + (lane & 15);
        float v = acc[mi][ni][j] + bias[col];
        if (MODE == 0) {
            ((__hip_bfloat16*)Cout)[(size_t)row * N + col] = __float2bfloat16(v);
        } else if (MODE == 2) {
            ((__hip_bfloat16*)Cout)[(size_t)row * N + col] =
                __float2bfloat16(0.5f * v * (1.f + erff(v * 0.70710678118654752f)));
        } else {
            int bb2 = row / KSEL, ss = row % KSEL;
            int pi = selidx[row];
            v += pos[(size_t)(1 + pi) * DIM + col];
            ((float*)Cout)[((size_t)bb2 * SEQ + 1 + ss) * DIM + col] = v;
        }
    }
}

// ---------------- V GEMM with transposed epilogue -> Vt[(b*3+h)][d][s] ------
// A = ln1-out y (ntok x 192), Wt = V rows of wt_qkv (192 x 192), grid (3,145)
// n0 = head*64. Pads s in [145,160) pre-zeroed by memset.
__global__ __launch_bounds__(256) void gemm_vt(const __hip_bfloat16* __restrict__ A,
                                               const __hip_bfloat16* __restrict__ Wt,
                                               const float* __restrict__ bias,
                                               __hip_bfloat16* __restrict__ Vt)
{
    __shared__ __align__(16) char As[8192];
    __shared__ __align__(16) char Bs[8192];
    const int tid = threadIdx.x;
    const int lane = tid & 63, wid = tid >> 6;
    const int wr = wid >> 1, wc = wid & 1;
    const int lr = lane & 15, lk = lane >> 4;
    const int m0 = blockIdx.y * 64, n0 = blockIdx.x * 64;
    const int K = DIM;
    f32x4 acc[2][2] = {};

    for (int k0 = 0; k0 < K; k0 += 64) {
#pragma unroll
        for (int it = 0; it < 2; ++it) {
            int chunk = it * 256 + tid;
            int r = chunk >> 3, g = chunk & 7;
            int loff = r * 128 + ((g ^ (r & 7)) * 16);
            *reinterpret_cast<uint4*>(As + loff) =
                *reinterpret_cast<const uint4*>(&A[(size_t)(m0 + r) * K + k0 + g * 8]);
            *reinterpret_cast<uint4*>(Bs + loff) =
                *reinterpret_cast<const uint4*>(&Wt[(size_t)(n0 + r) * K + k0 + g * 8]);
        }
        __syncthreads();
#pragma unroll
        for (int kc = 0; kc < 2; ++kc) {
            int g = kc * 4 + lk;
            bf16x8 af[2], bfr[2];
#pragma unroll
            for (int mi = 0; mi < 2; ++mi) {
                int r = wr * 32 + mi * 16 + lr;
                af[mi] = *reinterpret_cast<const bf16x8*>(As + r * 128 + ((g ^ (r & 7)) * 16));
            }
#pragma unroll
            for (int ni = 0; ni < 2; ++ni) {
                int r = wc * 32 + ni * 16 + lr;
                bfr[ni] = *reinterpret_cast<const bf16x8*>(Bs + r * 128 + ((g ^ (r & 7)) * 16));
            }
#pragma unroll
            for (int mi = 0; mi < 2; ++mi)
#pragma unroll
                for (int ni = 0; ni < 2; ++ni)
                    acc[mi][ni] = __builtin_amdgcn_mfma_f32_16x16x32_bf16(
                        af[mi], bfr[ni], acc[mi][ni], 0, 0, 0);
        }
        __syncthreads();
    }

#pragma unroll
    for (int mi = 0; mi < 2; ++mi)
#pragma unroll
    for (int ni = 0; ni < 2; ++ni)
#pragma unroll
    for (int j = 0; j < 4; ++j) {
        int row = m0 + wr * 32 + mi * 16 + (lane >> 4) * 4 + j;   // token
        int c   = n0 + wc * 32 + ni * 16 + (lane & 15);           // 0..191
        float v = acc[mi][ni][j] + bias[c];
        int b = row / SEQ, s = row - b * SEQ;
        Vt[((size_t)(b * 3 + (c >> 6)) * 64 + (c & 63)) * 160 + s] = __float2bfloat16(v);
    }
}

// ---------------- fused GEMM(192-out) + bias + residual + LayerNorm ---------
// Full-row blocks: grid(M/64), each block computes 64 rows x all 192 cols.
// Wave w owns rows w*16..w*16+15 (12 col-frags). Writes h (f32) and, if
// DO_LN, y = LN(h) in bf16 (params ls/lb).
template <bool DO_LN>
__global__ __launch_bounds__(256) void gemm_res_ln(const __hip_bfloat16* __restrict__ A,
                                                   const __hip_bfloat16* __restrict__ Wt,
                                                   const float* __restrict__ bias,
                                                   float* __restrict__ h,
                                                   const float* __restrict__ ls,
                                                   const float* __restrict__ lb,
                                                   __hip_bfloat16* __restrict__ y,
                                                   int K)
{
    __shared__ __align__(16) char As[8192];    // 64 x 64 bf16 swizzled
    __shared__ __align__(16) char Bs[24576];   // 192 x 64 bf16 swizzled
    const int tid = threadIdx.x;
    const int lane = tid & 63, w = tid >> 6;
    const int lr = lane & 15, lg = lane >> 4;
    const int m0 = blockIdx.x * 64;
    f32x4 acc[12] = {};

    for (int k0 = 0; k0 < K; k0 += 64) {
        {
            int chunk = tid;
#pragma unroll
            for (int it = 0; it < 2; ++it, chunk += 256) {
                int r = chunk >> 3, g = chunk & 7;
                *reinterpret_cast<uint4*>(As + r * 128 + ((g ^ (r & 7)) * 16)) =
                    *reinterpret_cast<const uint4*>(&A[(size_t)(m0 + r) * K + k0 + g * 8]);
            }
        }
        {
            int chunk = tid;
#pragma unroll
            for (int it = 0; it < 6; ++it, chunk += 256) {
                int r = chunk >> 3, g = chunk & 7;
                *reinterpret_cast<uint4*>(Bs + r * 128 + ((g ^ (r & 7)) * 16)) =
                    *reinterpret_cast<const uint4*>(&Wt[(size_t)r * K + k0 + g * 8]);
            }
        }
        __syncthreads();
#pragma unroll
        for (int kc = 0; kc < 2; ++kc) {
            int g = kc * 4 + lg;
            int ar = w * 16 + lr;
            bf16x8 af = *reinterpret_cast<const bf16x8*>(As + ar * 128 + ((g ^ (ar & 7)) * 16));
#pragma unroll
            for (int nf = 0; nf < 12; ++nf) {
                int br = nf * 16 + lr;
                bf16x8 bfv = *reinterpret_cast<const bf16x8*>(Bs + br * 128 + ((g ^ (br & 7)) * 16));
                acc[nf] = __builtin_amdgcn_mfma_f32_16x16x32_bf16(af, bfv, acc[nf], 0, 0, 0);
            }
        }
        __syncthreads();
    }

    // epilogue: v = acc + bias + h; h = v; optional row LN -> y
    float v[12][4];
    float sum[4] = {0.f, 0.f, 0.f, 0.f};
#pragma unroll
    for (int nf = 0; nf < 12; ++nf) {
        int col = nf * 16 + lr;
#pragma unroll
        for (int j = 0; j < 4; ++j) {
            int row = m0 + w * 16 + lg * 4 + j;
            float t = acc[nf][j] + bias[col] + h[(size_t)row * DIM + col];
            v[nf][j] = t;
            h[(size_t)row * DIM + col] = t;
            sum[j] += t;
        }
    }
    if (DO_LN) {
#pragma unroll
        for (int j = 0; j < 4; ++j)
            for (int off = 1; off < 16; off <<= 1) sum[j] += __shfl_xor(sum[j], off);
        float mean[4], sq[4] = {0.f, 0.f, 0.f, 0.f};
#pragma unroll
        for (int j = 0; j < 4; ++j) mean[j] = sum[j] * (1.f / 192.f);
#pragma unroll
        for (int nf = 0; nf < 12; ++nf)
#pragma unroll
            for (int j = 0; j < 4; ++j) {
                float d = v[nf][j] - mean[j];
                sq[j] += d * d;
            }
#pragma unroll
        for (int j = 0; j < 4; ++j) {
            for (int off = 1; off < 16; off <<= 1) sq[j] += __shfl_xor(sq[j], off);
            sq[j] = rsqrtf(sq[j] * (1.f / 192.f) + 1e-6f);
        }
#pragma unroll
        for (int nf = 0; nf < 12; ++nf) {
            int col = nf * 16 + lr;
            float sc = ls[col], bc = lb[col];
#pragma unroll
            for (int j = 0; j < 4; ++j) {
                int row = m0 + w * 16 + lg * 4 + j;
                y[(size_t)row * DIM + col] =
                    __float2bfloat16((v[nf][j] - mean[j]) * sq[j] * sc + bc);
            }
        }
    }
}

// ---------------- attention v3: MFMA, block=(b,h,qtile of 32), 2 waves ------
__global__ __launch_bounds__(128) void attn3_kernel(const __hip_bfloat16* __restrict__ qk,
                                                    const __hip_bfloat16* __restrict__ Vt,
                                                    __hip_bfloat16* __restrict__ o)
{
    const int b = blockIdx.y;
    const int h = blockIdx.x / 5, qt = blockIdx.x % 5;
    const int tid = threadIdx.x;
    const int wq = tid >> 6, lane = tid & 63;
    const int lr = lane & 15, lg = lane >> 4;
    __shared__ __hip_bfloat16 Ps[2][16][168];

    const size_t qbase = (size_t)b * SEQ * 384;
    const int q0 = qt * 32 + wq * 16;

    bf16x8 aq[2];
#pragma unroll
    for (int ks = 0; ks < 2; ++ks)
        aq[ks] = *reinterpret_cast<const bf16x8*>(
            &qk[qbase + (size_t)(q0 + lr) * 384 + h * 64 + ks * 32 + lg * 8]);

    f32x4 sc[10];
#pragma unroll
    for (int nf = 0; nf < 10; ++nf) sc[nf] = (f32x4){0.f, 0.f, 0.f, 0.f};
#pragma unroll
    for (int nf = 0; nf < 10; ++nf) {
        int key = nf * 16 + lr;
#pragma unroll
        for (int ks = 0; ks < 2; ++ks) {
            bf16x8 bk = *reinterpret_cast<const bf16x8*>(
                &qk[qbase + (size_t)key * 384 + 192 + h * 64 + ks * 32 + lg * 8]);
            sc[nf] = __builtin_amdgcn_mfma_f32_16x16x32_bf16(aq[ks], bk, sc[nf], 0, 0, 0);
        }
    }

    float mx[4] = {-1e30f, -1e30f, -1e30f, -1e30f};
#pragma unroll
    for (int nf = 0; nf < 10; ++nf) {
        bool valid = nf * 16 + lr < SEQ;
#pragma unroll
        for (int j = 0; j < 4; ++j) {
            float v = valid ? sc[nf][j] * 0.125f : -1e30f;
            sc[nf][j] = v;
            mx[j] = fmaxf(mx[j], v);
        }
    }
#pragma unroll
    for (int j = 0; j < 4; ++j)
        for (int off = 1; off < 16; off <<= 1)
            mx[j] = fmaxf(mx[j], __shfl_xor(mx[j], off));
    float sm[4] = {0.f, 0.f, 0.f, 0.f};
#pragma unroll
    for (int nf = 0; nf < 10; ++nf)
#pragma unroll
        for (int j = 0; j < 4; ++j) {
            float p = __expf(sc[nf][j] - mx[j]);
            sc[nf][j] = p;
            sm[j] += p;
        }
#pragma unroll
    for (int j = 0; j < 4; ++j) {
        for (int off = 1; off < 16; off <<= 1) sm[j] += __shfl_xor(sm[j], off);
        sm[j] = 1.f / sm[j];
    }
#pragma unroll
    for (int nf = 0; nf < 10; ++nf) {
        int key = nf * 16 + lr;
#pragma unroll
        for (int j = 0; j < 4; ++j)
            Ps[wq][lg * 4 + j][key] = __float2bfloat16(sc[nf][j] * sm[j]);
    }
    __syncthreads();

    const __hip_bfloat16* vtb = &Vt[(size_t)(b * 3 + h) * 64 * 160];
    f32x4 oacc[4];
#pragma unroll
    for (int nf = 0; nf < 4; ++nf) oacc[nf] = (f32x4){0.f, 0.f, 0.f, 0.f};
#pragma unroll
    for (int ks = 0; ks < 5; ++ks) {
        bf16x8 ap = *reinterpret_cast<const bf16x8*>(&Ps[wq][lr][ks * 32 + lg * 8]);
#pragma unroll
        for (int nf = 0; nf < 4; ++nf) {
            bf16x8 bv = *reinterpret_cast<const bf16x8*>(
                &vtb[(size_t)(nf * 16 + lr) * 160 + ks * 32 + lg * 8]);
            oacc[nf] = __builtin_amdgcn_mfma_f32_16x16x32_bf16(ap, bv, oacc[nf], 0, 0, 0);
        }
    }
#pragma unroll
    for (int nf = 0; nf < 4; ++nf)
#pragma unroll
        for (int j = 0; j < 4; ++j) {
            int q = q0 + lg * 4 + j;
            if (q < SEQ)
                o[((size_t)b * SEQ + q) * DIM + h * 64 + nf * 16 + lr] =
                    __float2bfloat16(oacc[nf][j]);
        }
}

// ---------------- head: final LN of cls + (64,192)@(192,1000) ---------------
__global__ __launch_bounds__(256) void head_kernel(const float* __restrict__ h,
                                                   const float* __restrict__ nfs,
                                                   const float* __restrict__ nfb,
                                                   const float* __restrict__ hw,
                                                   const float* __restrict__ hb,
                                                   float* __restrict__ out)
{
    int b = blockIdx.x, t = threadIdx.x;
    __shared__ float y[DIM];
    __shared__ float red[4];
    float x = (t < DIM) ? h[(size_t)b * SEQ * DIM + t] : 0.f;
    float sum = x;
    for (int off = 32; off; off >>= 1) sum += __shfl_xor(sum, off);
    if ((t & 63) == 0) red[t >> 6] = sum;
    __syncthreads();
    float mean = (red[0] + red[1] + red[2] + red[3]) * (1.f / 192.f);
    __syncthreads();
    float d = (t < DIM) ? (x - mean) : 0.f;
    float v = d * d;
    for (int off = 32; off; off >>= 1) v += __shfl_xor(v, off);
    if ((t & 63) == 0) red[t >> 6] = v;
    __syncthreads();
    float var = (red[0] + red[1] + red[2] + red[3]) * (1.f / 192.f);
    float rs = rsqrtf(var + 1e-6f);
    if (t < DIM) y[t] = d * rs * nfs[t] + nfb[t];
    __syncthreads();
    for (int n = t; n < 1000; n += 256) {
        float acc = hb[n];
#pragma unroll 8
        for (int k = 0; k < DIM; ++k)
            acc = fmaf(y[k], hw[(size_t)k * 1000 + n], acc);
        out[(size_t)b * 1000 + n] = acc;
    }
}

// ---------------------------------------------------------------------------
extern "C" void kernel_launch(void* const* d_in, const int* in_sizes, int n_in,
                              void* d_out, int out_size, void* d_ws, size_t ws_size,
                              hipStream_t stream)
{
    const float* magno  = (const float*)d_in[0];
    const float* line   = (const float*)d_in[1];
    const float* conv_w = (const float*)d_in[2];
    const float* conv_b = (const float*)d_in[3];
    const float* pos    = (const float*)d_in[4];
    const float* cls    = (const float*)d_in[5];
    const float* ln1_s  = (const float*)d_in[6];
    const float* ln1_b  = (const float*)d_in[7];
    const float* qkv_w  = (const float*)d_in[8];
    const float* qkv_b  = (const float*)d_in[9];
    const float* proj_w = (const float*)d_in[10];
    const float* proj_b = (const float*)d_in[11];
    const float* ln2_s  = (const float*)d_in[12];
    const float* ln2_b  = (const float*)d_in[13];
    const float* fc1_w  = (const float*)d_in[14];
    const float* fc1_b  = (const float*)d_in[15];
    const float* fc2_w  = (const float*)d_in[16];
    const float* fc2_b  = (const float*)d_in[17];
    const float* normf_s = (const float*)d_in[18];
    const float* normf_b = (const float*)d_in[19];
    const float* head_w = (const float*)d_in[20];
    const float* head_b = (const float*)d_in[21];
    float* out = (float*)d_out;
    (void)in_sizes; (void)n_in; (void)out_size; (void)ws_size;

    // workspace layout (bytes), total ~46.8 MB
    char* ws = (char*)d_ws;
    int*            idx     = (int*)            (ws + 0);         //    36864 (pad)
    float*          h       = (float*)          (ws + 147456);    //  7127040
    __hip_bfloat16* y       = (__hip_bfloat16*) (ws + 7274496);   //  3563520
    __hip_bfloat16* qk      = (__hip_bfloat16*) (ws + 10838016);  //  7127040
    __hip_bfloat16* Vt      = (__hip_bfloat16*) (ws + 17965056);  //  3932160
    __hip_bfloat16* tbuf    = (__hip_bfloat16*) (ws + 21897216);  // 14254080
    __hip_bfloat16* wt_qkv  = (__hip_bfloat16*) (ws + 36151296);  //  2654208
    __hip_bfloat16* wt_proj = (__hip_bfloat16*) (ws + 38805504);  //   884736
    __hip_bfloat16* wt_fc1  = (__hip_bfloat16*) (ws + 39690240);  //  3538944
    __hip_bfloat16* wt_fc2  = (__hip_bfloat16*) (ws + 43229184);  //  3538944
    float*          scoresbuf = (float*)qk;             // alias (used before qk)
    __hip_bfloat16* convT     = y;                      // alias (used before y)
    __hip_bfloat16* selp      = tbuf;                   // alias (used before tbuf)

    // ---- prep: weights -> bf16 [N][K]; zero Vt pads once ----
    hipMemsetAsync(Vt, 0, 3932160, stream);
    transpose_w_kernel<<<dim3(18, 6, 12), 256, 0, stream>>>(qkv_w, wt_qkv, DIM, 576);
    transpose_w_kernel<<<dim3(6, 6, 12),  256, 0, stream>>>(proj_w, wt_proj, DIM, DIM);
    transpose_w_kernel<<<dim3(24, 6, 12), 256, 0, stream>>>(fc1_w, wt_fc1, DIM, HIDN);
    transpose_w_kernel<<<dim3(6, 24, 12), 256, 0, stream>>>(fc2_w, wt_fc2, HIDN, DIM);
    convert_bf16_kernel<<<576, 256, 0, stream>>>(conv_w, convT, DIM * 768);

    // ---- patch selection + embed ----
    scores_kernel<<<Bsz * NPATCH, 256, 0, stream>>>(line, scoresbuf);
    topk_kernel<<<Bsz, 256, 0, stream>>>(scoresbuf, idx);
    gather_kernel<<<Bsz * KSEL, 256, 0, stream>>>(magno, idx, selp);
    cls_kernel<<<Bsz, DIM, 0, stream>>>(cls, pos, h);
    gemm_bf16<3><<<dim3(3, 144), 256, 0, stream>>>(selp, convT, conv_b, h,
                                                   9216, DIM, 768, idx, pos);

    const int ntok = Bsz * SEQ;              // 9280 = 145*64
    ln_kernel<<<ntok / 4, 256, 0, stream>>>(h, ln1_s, ln1_b, y, ntok);
    for (int l = 0; l < 12; ++l) {
        // QK projection (N=384) + V projection with transposed epilogue
        gemm_bf16<0><<<dim3(6, 145), 256, 0, stream>>>(y, wt_qkv + (size_t)l * 576 * DIM,
                                                       qkv_b + l * 576, qk,
                                                       ntok, 384, DIM, nullptr, nullptr);
        gemm_vt<<<dim3(3, 145), 256, 0, stream>>>(y, wt_qkv + (size_t)l * 576 * DIM + 384 * DIM,
                                                  qkv_b + l * 576 + 384, Vt);
        attn3_kernel<<<dim3(15, Bsz), 128, 0, stream>>>(qk, Vt, y);
        // proj + bias + residual + ln2 -> h, y
        gemm_res_ln<true><<<145, 256, 0, stream>>>(y, wt_proj + (size_t)l * DIM * DIM,
                                                   proj_b + l * DIM, h,
                                                   ln2_s + l * DIM, ln2_b + l * DIM, y, DIM);
        gemm_bf16<2><<<dim3(12, 145), 256, 0, stream>>>(y, wt_fc1 + (size_t)l * HIDN * DIM,
                                                        fc1_b + l * HIDN, tbuf,
                                                        ntok, HIDN, DIM, nullptr, nullptr);
        // fc2 + bias + residual (+ next layer's ln1) -> h, y
        if (l < 11)
            gemm_res_ln<true><<<145, 256, 0, stream>>>(tbuf, wt_fc2 + (size_t)l * DIM * HIDN,
                                                       fc2_b + l * DIM, h,
                                                       ln1_s + (l + 1) * DIM, ln1_b + (l + 1) * DIM,
                                                       y, HIDN);
        else
            gemm_res_ln<false><<<145, 256, 0, stream>>>(tbuf, wt_fc2 + (size_t)l * DIM * HIDN,
                                                        fc2_b + l * DIM, h,
                                                        nullptr, nullptr, y, HIDN);
    }
    head_kernel<<<Bsz, 256, 0, stream>>>(h, normf_s, normf_b, head_w, head_b, out);
}

// Round 6
// 940.828 us; speedup vs baseline: 5.0923x; 1.0309x over previous
//
#include <hip/hip_runtime.h>
#include <hip/hip_bf16.h>
#include <cmath>

// ---------------------------------------------------------------------------
// SelectiveMagnoViT forward. Round 5: per-layer chain cut to 4 dispatches:
//   gemm_qkv (qk store + V^T scatter) -> attnproj (attn+proj+res+ln2 fused)
//   -> fc1 (gelu) -> fc2 (res+ln1' fused).
// ---------------------------------------------------------------------------

#define Bsz   64
#define NPATCH 576
#define KSEL  144
#define SEQ   145
#define DIM   192
#define HIDN  768

typedef __bf16 bf16x8 __attribute__((ext_vector_type(8)));
typedef float  f32x4  __attribute__((ext_vector_type(4)));

// ---------------- patch scores: 16x16 average pool of line drawing ----------
__global__ __launch_bounds__(256) void scores_kernel(const float* __restrict__ line,
                                                     float* __restrict__ scores)
{
    int gp = blockIdx.x;              // b*576 + p
    int b = gp / NPATCH, p = gp % NPATCH;
    int gy = p / 24, gx = p % 24;
    int t = threadIdx.x, py = t >> 4, px = t & 15;
    float v = line[((size_t)b * 384 + gy * 16 + py) * 384 + gx * 16 + px];
    for (int off = 32; off; off >>= 1) v += __shfl_xor(v, off);
    __shared__ float red[4];
    if ((t & 63) == 0) red[t >> 6] = v;
    __syncthreads();
    if (t == 0) scores[gp] = (red[0] + red[1] + red[2] + red[3]) * (1.f / 256.f);
}

// ---------------- exact top-k via rank scatter (jax order, no serial) -------
__global__ __launch_bounds__(256) void topk_kernel(const float* __restrict__ scores,
                                                   int* __restrict__ idx)
{
    int b = blockIdx.x;
    __shared__ float s[NPATCH];
    for (int i = threadIdx.x; i < NPATCH; i += 256) s[i] = scores[b * NPATCH + i];
    __syncthreads();
    for (int i = threadIdx.x; i < NPATCH; i += 256) {
        float si = s[i];
        int cnt = 0;
        for (int j = 0; j < NPATCH; ++j) {
            float sj = s[j];
            cnt += (sj > si) || (sj == si && j < i);
        }
        if (cnt < KSEL) idx[b * KSEL + cnt] = i;
    }
}

// ---------------- gather selected patches into bf16 (B*144, 768) ------------
__global__ __launch_bounds__(256) void gather_kernel(const float* __restrict__ magno,
                                                     const int* __restrict__ idx,
                                                     __hip_bfloat16* __restrict__ selp)
{
    int bs = blockIdx.x;              // b*144 + s
    int b = bs / KSEL;
    int pi = idx[bs];
    int gy = pi / 24, gx = pi % 24;
    int t = threadIdx.x, py = t >> 4, px = t & 15;
    size_t src = ((size_t)b * 3 * 384 + gy * 16 + py) * 384 + gx * 16 + px;
    __hip_bfloat16* dst = &selp[(size_t)bs * 768];
#pragma unroll
    for (int c = 0; c < 3; ++c)
        dst[c * 256 + t] = __float2bfloat16(magno[src + (size_t)c * 384 * 384]);
}

// ---------------- f32 -> bf16 elementwise (conv_w, already [N][K]) ----------
__global__ __launch_bounds__(256) void convert_bf16_kernel(const float* __restrict__ src,
                                                           __hip_bfloat16* __restrict__ dst,
                                                           int n)
{
    int i = blockIdx.x * 256 + threadIdx.x;
    if (i < n) dst[i] = __float2bfloat16(src[i]);
}

// ---------------- per-layer transpose+convert: src[l][R][C] -> dst[l][C][R] -
__global__ __launch_bounds__(256) void transpose_w_kernel(const float* __restrict__ src,
                                                          __hip_bfloat16* __restrict__ dst,
                                                          int R, int C)
{
    __shared__ float t[32][33];
    size_t lo = (size_t)blockIdx.z * R * C;
    int r0 = blockIdx.y * 32, c0 = blockIdx.x * 32;
    int tx = threadIdx.x & 31, ty = threadIdx.x >> 5;   // 8 rows per pass
#pragma unroll
    for (int i = 0; i < 32; i += 8)
        t[ty + i][tx] = src[lo + (size_t)(r0 + ty + i) * C + c0 + tx];
    __syncthreads();
#pragma unroll
    for (int i = 0; i < 32; i += 8)
        dst[lo + (size_t)(c0 + ty + i) * R + r0 + tx] = __float2bfloat16(t[tx][ty + i]);
}

// ---------------- cls token init --------------------------------------------
__global__ void cls_kernel(const float* __restrict__ cls, const float* __restrict__ pos,
                           float* __restrict__ h)
{
    int b = blockIdx.x, t = threadIdx.x;      // 192 threads
    h[(size_t)b * SEQ * DIM + t] = cls[t] + pos[t];
}

// ---------------- LayerNorm over D=192 -> bf16 out (layer-0 ln1 only) -------
__global__ __launch_bounds__(256) void ln_kernel(const float* __restrict__ x,
                                                 const float* __restrict__ s,
                                                 const float* __restrict__ bia,
                                                 __hip_bfloat16* __restrict__ y, int ntok)
{
    int w = threadIdx.x >> 6, lane = threadIdx.x & 63;
    int tok = blockIdx.x * 4 + w;
    if (tok >= ntok) return;
    const float* xp = &x[(size_t)tok * DIM];
    float x0 = xp[lane], x1 = xp[lane + 64], x2 = xp[lane + 128];
    float sum = x0 + x1 + x2;
    for (int off = 32; off; off >>= 1) sum += __shfl_xor(sum, off);
    float mean = sum * (1.f / 192.f);
    float d0 = x0 - mean, d1 = x1 - mean, d2 = x2 - mean;
    float vs = d0 * d0 + d1 * d1 + d2 * d2;
    for (int off = 32; off; off >>= 1) vs += __shfl_xor(vs, off);
    float rs = rsqrtf(vs * (1.f / 192.f) + 1e-6f);
    __hip_bfloat16* yp = &y[(size_t)tok * DIM];
    yp[lane]       = __float2bfloat16(d0 * rs * s[lane]       + bia[lane]);
    yp[lane + 64]  = __float2bfloat16(d1 * rs * s[lane + 64]  + bia[lane + 64]);
    yp[lane + 128] = __float2bfloat16(d2 * rs * s[lane + 128] + bia[lane + 128]);
}

// ---------------- bf16 MFMA GEMM: C = A(M,K)bf16 @ Wt(N,K)bf16^T + bias -----
// MODE 2: gelu -> bf16   MODE 3: patch embed -> f32 h
template <int MODE>
__global__ __launch_bounds__(256) void gemm_bf16(const __hip_bfloat16* __restrict__ A,
                                                 const __hip_bfloat16* __restrict__ Wt,
                                                 const float* __restrict__ bias,
                                                 void* __restrict__ Cout,
                                                 int M, int N, int K,
                                                 const int* __restrict__ selidx,
                                                 const float* __restrict__ pos)
{
    __shared__ __align__(16) char As[8192];   // 64 rows x 64 bf16 (swizzled)
    __shared__ __align__(16) char Bs[8192];
    const int tid = threadIdx.x;
    const int lane = tid & 63, wid = tid >> 6;
    const int wr = wid >> 1, wc = wid & 1;
    const int lr = lane & 15, lk = lane >> 4;
    const int m0 = blockIdx.y * 64, n0 = blockIdx.x * 64;
    f32x4 acc[2][2] = {};

    for (int k0 = 0; k0 < K; k0 += 64) {
#pragma unroll
        for (int it = 0; it < 2; ++it) {
            int chunk = it * 256 + tid;          // 0..511
            int r = chunk >> 3, g = chunk & 7;
            int loff = r * 128 + ((g ^ (r & 7)) * 16);
            *reinterpret_cast<uint4*>(As + loff) =
                *reinterpret_cast<const uint4*>(&A[(size_t)(m0 + r) * K + k0 + g * 8]);
            *reinterpret_cast<uint4*>(Bs + loff) =
                *reinterpret_cast<const uint4*>(&Wt[(size_t)(n0 + r) * K + k0 + g * 8]);
        }
        __syncthreads();
#pragma unroll
        for (int kc = 0; kc < 2; ++kc) {
            int g = kc * 4 + lk;                 // 8-elem k-group within row
            bf16x8 af[2], bfr[2];
#pragma unroll
            for (int mi = 0; mi < 2; ++mi) {
                int r = wr * 32 + mi * 16 + lr;
                af[mi] = *reinterpret_cast<const bf16x8*>(As + r * 128 + ((g ^ (r & 7)) * 16));
            }
#pragma unroll
            for (int ni = 0; ni < 2; ++ni) {
                int r = wc * 32 + ni * 16 + lr;
                bfr[ni] = *reinterpret_cast<const bf16x8*>(Bs + r * 128 + ((g ^ (r & 7)) * 16));
            }
#pragma unroll
            for (int mi = 0; mi < 2; ++mi)
#pragma unroll
                for (int ni = 0; ni < 2; ++ni)
                    acc[mi][ni] = __builtin_amdgcn_mfma_f32_16x16x32_bf16(
                        af[mi], bfr[ni], acc[mi][ni], 0, 0, 0);
        }
        __syncthreads();
    }

#pragma unroll
    for (int mi = 0; mi < 2; ++mi)
#pragma unroll
    for (int ni = 0; ni < 2; ++ni)
#pragma unroll
    for (int j = 0; j < 4; ++j) {
        int row = m0 + wr * 32 + mi * 16 + (lane >> 4) * 4 + j;
        int col = n0 + wc * 32 + ni * 16 + (lane & 15);
        float v = acc[mi][ni][j] + bias[col];
        if (MODE == 2) {
            ((__hip_bfloat16*)Cout)[(size_t)row * N + col] =
                __float2bfloat16(0.5f * v * (1.f + erff(v * 0.70710678118654752f)));
        } else {
            int bb2 = row / KSEL, ss = row % KSEL;
            int pi = selidx[row];
            v += pos[(size_t)(1 + pi) * DIM + col];
            ((float*)Cout)[((size_t)bb2 * SEQ + 1 + ss) * DIM + col] = v;
        }
    }
}

// ---------------- qkv GEMM: N=576; cols<384 -> qk; cols>=384 -> Vt^T --------
// A (ntok x 192) bf16, Wt (576 x 192) bf16. Grid (9, 145).
__global__ __launch_bounds__(256) void gemm_qkv(const __hip_bfloat16* __restrict__ A,
                                                const __hip_bfloat16* __restrict__ Wt,
                                                const float* __restrict__ bias,
                                                __hip_bfloat16* __restrict__ qk,
                                                __hip_bfloat16* __restrict__ Vt)
{
    __shared__ __align__(16) char As[8192];
    __shared__ __align__(16) char Bs[8192];
    const int tid = threadIdx.x;
    const int lane = tid & 63, wid = tid >> 6;
    const int wr = wid >> 1, wc = wid & 1;
    const int lr = lane & 15, lk = lane >> 4;
    const int m0 = blockIdx.y * 64, n0 = blockIdx.x * 64;
    const int K = DIM;
    f32x4 acc[2][2] = {};

    for (int k0 = 0; k0 < K; k0 += 64) {
#pragma unroll
        for (int it = 0; it < 2; ++it) {
            int chunk = it * 256 + tid;
            int r = chunk >> 3, g = chunk & 7;
            int loff = r * 128 + ((g ^ (r & 7)) * 16);
            *reinterpret_cast<uint4*>(As + loff) =
                *reinterpret_cast<const uint4*>(&A[(size_t)(m0 + r) * K + k0 + g * 8]);
            *reinterpret_cast<uint4*>(Bs + loff) =
                *reinterpret_cast<const uint4*>(&Wt[(size_t)(n0 + r) * K + k0 + g * 8]);
        }
        __syncthreads();
#pragma unroll
        for (int kc = 0; kc < 2; ++kc) {
            int g = kc * 4 + lk;
            bf16x8 af[2], bfr[2];
#pragma unroll
            for (int mi = 0; mi < 2; ++mi) {
                int r = wr * 32 + mi * 16 + lr;
                af[mi] = *reinterpret_cast<const bf16x8*>(As + r * 128 + ((g ^ (r & 7)) * 16));
            }
#pragma unroll
            for (int ni = 0; ni < 2; ++ni) {
                int r = wc * 32 + ni * 16 + lr;
                bfr[ni] = *reinterpret_cast<const bf16x8*>(Bs + r * 128 + ((g ^ (r & 7)) * 16));
            }
#pragma unroll
            for (int mi = 0; mi < 2; ++mi)
#pragma unroll
                for (int ni = 0; ni < 2; ++ni)
                    acc[mi][ni] = __builtin_amdgcn_mfma_f32_16x16x32_bf16(
                        af[mi], bfr[ni], acc[mi][ni], 0, 0, 0);
        }
        __syncthreads();
    }

#pragma unroll
    for (int mi = 0; mi < 2; ++mi)
#pragma unroll
    for (int ni = 0; ni < 2; ++ni)
#pragma unroll
    for (int j = 0; j < 4; ++j) {
        int row = m0 + wr * 32 + mi * 16 + (lane >> 4) * 4 + j;
        int col = n0 + wc * 32 + ni * 16 + (lane & 15);
        float v = acc[mi][ni][j] + bias[col];
        if (col < 384) {
            qk[(size_t)row * 384 + col] = __float2bfloat16(v);
        } else {
            int c = col - 384;
            int b = row / SEQ, s = row - b * SEQ;
            Vt[((size_t)(b * 3 + (c >> 6)) * 64 + (c & 63)) * 160 + s] = __float2bfloat16(v);
        }
    }
}

// ---------------- fused attention + proj + bias + residual + ln2 ------------
// Grid (5, 64) = (qtile of 32, batch). 4 waves. Waves 0..2 = heads (QK^T,
// softmax, PV -> O tile in LDS); wave 3 idles phase 1. Phase 2: all 4 waves
// proj O(32x192) @ Wp^T, + bias + residual h, LN(ln2) -> y bf16, h f32.
__global__ __launch_bounds__(256) void attnproj_kernel(const __hip_bfloat16* __restrict__ qk,
                                                       const __hip_bfloat16* __restrict__ Vt,
                                                       const __hip_bfloat16* __restrict__ Wp,
                                                       const float* __restrict__ pbias,
                                                       float* __restrict__ h,
                                                       const float* __restrict__ ls,
                                                       const float* __restrict__ lb,
                                                       __hip_bfloat16* __restrict__ y)
{
    const int b = blockIdx.y, qt = blockIdx.x;
    const int tid = threadIdx.x;
    const int w = tid >> 6, lane = tid & 63;
    const int lr = lane & 15, lg = lane >> 4;
    __shared__ __hip_bfloat16 Ps[3][32][168];
    __shared__ __hip_bfloat16 Ot[32][200];
    __shared__ float redsum[4][32];
    __shared__ float redsq[4][32];

    const size_t qbase = (size_t)b * SEQ * 384;
    const int q0 = qt * 32;

    if (w < 3) {
        const int hh = w;
        // ---- QK^T: 2 m-frags x 10 n-frags x 2 k-steps ----
        bf16x8 aq[2][2];
#pragma unroll
        for (int mi = 0; mi < 2; ++mi)
#pragma unroll
            for (int ks = 0; ks < 2; ++ks)
                aq[mi][ks] = *reinterpret_cast<const bf16x8*>(
                    &qk[qbase + (size_t)(q0 + mi * 16 + lr) * 384 + hh * 64 + ks * 32 + lg * 8]);
        f32x4 sc[2][10];
#pragma unroll
        for (int mi = 0; mi < 2; ++mi)
#pragma unroll
            for (int nf = 0; nf < 10; ++nf) sc[mi][nf] = (f32x4){0.f, 0.f, 0.f, 0.f};
#pragma unroll
        for (int nf = 0; nf < 10; ++nf) {
            int key = nf * 16 + lr;
#pragma unroll
            for (int ks = 0; ks < 2; ++ks) {
                bf16x8 bk = *reinterpret_cast<const bf16x8*>(
                    &qk[qbase + (size_t)key * 384 + 192 + hh * 64 + ks * 32 + lg * 8]);
#pragma unroll
                for (int mi = 0; mi < 2; ++mi)
                    sc[mi][nf] = __builtin_amdgcn_mfma_f32_16x16x32_bf16(
                        aq[mi][ks], bk, sc[mi][nf], 0, 0, 0);
            }
        }
        // ---- softmax (rows = mi*16 + lg*4 + j; cols over lr x nf) ----
#pragma unroll
        for (int mi = 0; mi < 2; ++mi) {
            float mx[4] = {-1e30f, -1e30f, -1e30f, -1e30f};
#pragma unroll
            for (int nf = 0; nf < 10; ++nf) {
                bool valid = nf * 16 + lr < SEQ;
#pragma unroll
                for (int j = 0; j < 4; ++j) {
                    float v = valid ? sc[mi][nf][j] * 0.125f : -1e30f;
                    sc[mi][nf][j] = v;
                    mx[j] = fmaxf(mx[j], v);
                }
            }
#pragma unroll
            for (int j = 0; j < 4; ++j)
                for (int off = 1; off < 16; off <<= 1)
                    mx[j] = fmaxf(mx[j], __shfl_xor(mx[j], off));
            float sm[4] = {0.f, 0.f, 0.f, 0.f};
#pragma unroll
            for (int nf = 0; nf < 10; ++nf)
#pragma unroll
                for (int j = 0; j < 4; ++j) {
                    float p = __expf(sc[mi][nf][j] - mx[j]);
                    sc[mi][nf][j] = p;
                    sm[j] += p;
                }
#pragma unroll
            for (int j = 0; j < 4; ++j) {
                for (int off = 1; off < 16; off <<= 1) sm[j] += __shfl_xor(sm[j], off);
                sm[j] = 1.f / sm[j];
            }
#pragma unroll
            for (int nf = 0; nf < 10; ++nf) {
                int key = nf * 16 + lr;
#pragma unroll
                for (int j = 0; j < 4; ++j)
                    Ps[hh][mi * 16 + lg * 4 + j][key] = __float2bfloat16(sc[mi][nf][j] * sm[j]);
            }
        }
        // ---- PV: A = P (same-wave LDS), B = Vt ----
        const __hip_bfloat16* vtb = &Vt[(size_t)(b * 3 + hh) * 64 * 160];
        f32x4 oacc[2][4];
#pragma unroll
        for (int mi = 0; mi < 2; ++mi)
#pragma unroll
            for (int nf = 0; nf < 4; ++nf) oacc[mi][nf] = (f32x4){0.f, 0.f, 0.f, 0.f};
#pragma unroll
        for (int ks = 0; ks < 5; ++ks) {
            bf16x8 ap[2];
            ap[0] = *reinterpret_cast<const bf16x8*>(&Ps[hh][lr][ks * 32 + lg * 8]);
            ap[1] = *reinterpret_cast<const bf16x8*>(&Ps[hh][16 + lr][ks * 32 + lg * 8]);
#pragma unroll
            for (int nf = 0; nf < 4; ++nf) {
                bf16x8 bv = *reinterpret_cast<const bf16x8*>(
                    &vtb[(size_t)(nf * 16 + lr) * 160 + ks * 32 + lg * 8]);
#pragma unroll
                for (int mi = 0; mi < 2; ++mi)
                    oacc[mi][nf] = __builtin_amdgcn_mfma_f32_16x16x32_bf16(
                        ap[mi], bv, oacc[mi][nf], 0, 0, 0);
            }
        }
#pragma unroll
        for (int mi = 0; mi < 2; ++mi)
#pragma unroll
            for (int nf = 0; nf < 4; ++nf)
#pragma unroll
                for (int j = 0; j < 4; ++j)
                    Ot[mi * 16 + lg * 4 + j][hh * 64 + nf * 16 + lr] =
                        __float2bfloat16(oacc[mi][nf][j]);
    }
    __syncthreads();

    // ---- proj: all 4 waves; wave covers cols w*48..w*48+47 ----
    f32x4 pacc[2][3];
#pragma unroll
    for (int mi = 0; mi < 2; ++mi)
#pragma unroll
        for (int nf = 0; nf < 3; ++nf) pacc[mi][nf] = (f32x4){0.f, 0.f, 0.f, 0.f};
#pragma unroll
    for (int kk = 0; kk < 6; ++kk) {
        bf16x8 af[2];
        af[0] = *reinterpret_cast<const bf16x8*>(&Ot[lr][kk * 32 + lg * 8]);
        af[1] = *reinterpret_cast<const bf16x8*>(&Ot[16 + lr][kk * 32 + lg * 8]);
#pragma unroll
        for (int nf = 0; nf < 3; ++nf) {
            int ncol = w * 48 + nf * 16 + lr;
            bf16x8 bw = *reinterpret_cast<const bf16x8*>(&Wp[(size_t)ncol * 192 + kk * 32 + lg * 8]);
#pragma unroll
            for (int mi = 0; mi < 2; ++mi)
                pacc[mi][nf] = __builtin_amdgcn_mfma_f32_16x16x32_bf16(
                    af[mi], bw, pacc[mi][nf], 0, 0, 0);
        }
    }
    // ---- epilogue: + bias + residual; cross-wave LN (E[x^2]-m^2) ----
    float v[2][3][4];
    float psum[2][4] = {}, psq[2][4] = {};
#pragma unroll
    for (int mi = 0; mi < 2; ++mi)
#pragma unroll
    for (int nf = 0; nf < 3; ++nf) {
        int col = w * 48 + nf * 16 + lr;
        float bcol = pbias[col];
#pragma unroll
        for (int j = 0; j < 4; ++j) {
            int q = q0 + mi * 16 + lg * 4 + j;
            float res = (q < SEQ) ? h[((size_t)b * SEQ + q) * DIM + col] : 0.f;
            float t = pacc[mi][nf][j] + bcol + res;
            v[mi][nf][j] = t;
            psum[mi][j] += t;
            psq[mi][j] += t * t;
        }
    }
#pragma unroll
    for (int mi = 0; mi < 2; ++mi)
#pragma unroll
        for (int j = 0; j < 4; ++j) {
            for (int off = 1; off < 16; off <<= 1) {
                psum[mi][j] += __shfl_xor(psum[mi][j], off);
                psq[mi][j]  += __shfl_xor(psq[mi][j], off);
            }
            redsum[w][mi * 16 + lg * 4 + j] = psum[mi][j];
            redsq[w][mi * 16 + lg * 4 + j]  = psq[mi][j];
        }
    __syncthreads();
#pragma unroll
    for (int mi = 0; mi < 2; ++mi) {
#pragma unroll
        for (int j = 0; j < 4; ++j) {
            int r = mi * 16 + lg * 4 + j;
            int q = q0 + r;
            if (q >= SEQ) continue;
            float tsum = redsum[0][r] + redsum[1][r] + redsum[2][r] + redsum[3][r];
            float tsq  = redsq[0][r]  + redsq[1][r]  + redsq[2][r]  + redsq[3][r];
            float mean = tsum * (1.f / 192.f);
            float var  = tsq * (1.f / 192.f) - mean * mean;
            float rs = rsqrtf(var + 1e-6f);
#pragma unroll
            for (int nf = 0; nf < 3; ++nf) {
                int col = w * 48 + nf * 16 + lr;
                float t = v[mi][nf][j];
                h[((size_t)b * SEQ + q) * DIM + col] = t;
                y[((size_t)b * SEQ + q) * DIM + col] =
                    __float2bfloat16((t - mean) * rs * ls[col] + lb[col]);
            }
        }
    }
}

// ---------------- fused GEMM(192-out) + bias + residual + LayerNorm ---------
template <bool DO_LN>
__global__ __launch_bounds__(256) void gemm_res_ln(const __hip_bfloat16* __restrict__ A,
                                                   const __hip_bfloat16* __restrict__ Wt,
                                                   const float* __restrict__ bias,
                                                   float* __restrict__ h,
                                                   const float* __restrict__ ls,
                                                   const float* __restrict__ lb,
                                                   __hip_bfloat16* __restrict__ y,
                                                   int K)
{
    __shared__ __align__(16) char As[8192];    // 64 x 64 bf16 swizzled
    __shared__ __align__(16) char Bs[24576];   // 192 x 64 bf16 swizzled
    const int tid = threadIdx.x;
    const int lane = tid & 63, w = tid >> 6;
    const int lr = lane & 15, lg = lane >> 4;
    const int m0 = blockIdx.x * 64;
    f32x4 acc[12] = {};

    for (int k0 = 0; k0 < K; k0 += 64) {
        {
            int chunk = tid;
#pragma unroll
            for (int it = 0; it < 2; ++it, chunk += 256) {
                int r = chunk >> 3, g = chunk & 7;
                *reinterpret_cast<uint4*>(As + r * 128 + ((g ^ (r & 7)) * 16)) =
                    *reinterpret_cast<const uint4*>(&A[(size_t)(m0 + r) * K + k0 + g * 8]);
            }
        }
        {
            int chunk = tid;
#pragma unroll
            for (int it = 0; it < 6; ++it, chunk += 256) {
                int r = chunk >> 3, g = chunk & 7;
                *reinterpret_cast<uint4*>(Bs + r * 128 + ((g ^ (r & 7)) * 16)) =
                    *reinterpret_cast<const uint4*>(&Wt[(size_t)r * K + k0 + g * 8]);
            }
        }
        __syncthreads();
#pragma unroll
        for (int kc = 0; kc < 2; ++kc) {
            int g = kc * 4 + lg;
            int ar = w * 16 + lr;
            bf16x8 af = *reinterpret_cast<const bf16x8*>(As + ar * 128 + ((g ^ (ar & 7)) * 16));
#pragma unroll
            for (int nf = 0; nf < 12; ++nf) {
                int br = nf * 16 + lr;
                bf16x8 bfv = *reinterpret_cast<const bf16x8*>(Bs + br * 128 + ((g ^ (br & 7)) * 16));
                acc[nf] = __builtin_amdgcn_mfma_f32_16x16x32_bf16(af, bfv, acc[nf], 0, 0, 0);
            }
        }
        __syncthreads();
    }

    float v[12][4];
    float sum[4] = {0.f, 0.f, 0.f, 0.f};
#pragma unroll
    for (int nf = 0; nf < 12; ++nf) {
        int col = nf * 16 + lr;
#pragma unroll
        for (int j = 0; j < 4; ++j) {
            int row = m0 + w * 16 + lg * 4 + j;
            float t = acc[nf][j] + bias[col] + h[(size_t)row * DIM + col];
            v[nf][j] = t;
            h[(size_t)row * DIM + col] = t;
            sum[j] += t;
        }
    }
    if (DO_LN) {
#pragma unroll
        for (int j = 0; j < 4; ++j)
            for (int off = 1; off < 16; off <<= 1) sum[j] += __shfl_xor(sum[j], off);
        float mean[4], sq[4] = {0.f, 0.f, 0.f, 0.f};
#pragma unroll
        for (int j = 0; j < 4; ++j) mean[j] = sum[j] * (1.f / 192.f);
#pragma unroll
        for (int nf = 0; nf < 12; ++nf)
#pragma unroll
            for (int j = 0; j < 4; ++j) {
                float d = v[nf][j] - mean[j];
                sq[j] += d * d;
            }
#pragma unroll
        for (int j = 0; j < 4; ++j) {
            for (int off = 1; off < 16; off <<= 1) sq[j] += __shfl_xor(sq[j], off);
            sq[j] = rsqrtf(sq[j] * (1.f / 192.f) + 1e-6f);
        }
#pragma unroll
        for (int nf = 0; nf < 12; ++nf) {
            int col = nf * 16 + lr;
            float sc = ls[col], bc = lb[col];
#pragma unroll
            for (int j = 0; j < 4; ++j) {
                int row = m0 + w * 16 + lg * 4 + j;
                y[(size_t)row * DIM + col] =
                    __float2bfloat16((v[nf][j] - mean[j]) * sq[j] * sc + bc);
            }
        }
    }
}

// ---------------- head: final LN of cls + (64,192)@(192,1000) ---------------
__global__ __launch_bounds__(256) void head_kernel(const float* __restrict__ h,
                                                   const float* __restrict__ nfs,
                                                   const float* __restrict__ nfb,
                                                   const float* __restrict__ hw,
                                                   const float* __restrict__ hb,
                                                   float* __restrict__ out)
{
    int b = blockIdx.x, t = threadIdx.x;
    __shared__ float y[DIM];
    __shared__ float red[4];
    float x = (t < DIM) ? h[(size_t)b * SEQ * DIM + t] : 0.f;
    float sum = x;
    for (int off = 32; off; off >>= 1) sum += __shfl_xor(sum, off);
    if ((t & 63) == 0) red[t >> 6] = sum;
    __syncthreads();
    float mean = (red[0] + red[1] + red[2] + red[3]) * (1.f / 192.f);
    __syncthreads();
    float d = (t < DIM) ? (x - mean) : 0.f;
    float v = d * d;
    for (int off = 32; off; off >>= 1) v += __shfl_xor(v, off);
    if ((t & 63) == 0) red[t >> 6] = v;
    __syncthreads();
    float var = (red[0] + red[1] + red[2] + red[3]) * (1.f / 192.f);
    float rs = rsqrtf(var + 1e-6f);
    if (t < DIM) y[t] = d * rs * nfs[t] + nfb[t];
    __syncthreads();
    for (int n = t; n < 1000; n += 256) {
        float acc = hb[n];
#pragma unroll 8
        for (int k = 0; k < DIM; ++k)
            acc = fmaf(y[k], hw[(size_t)k * 1000 + n], acc);
        out[(size_t)b * 1000 + n] = acc;
    }
}

// ---------------------------------------------------------------------------
extern "C" void kernel_launch(void* const* d_in, const int* in_sizes, int n_in,
                              void* d_out, int out_size, void* d_ws, size_t ws_size,
                              hipStream_t stream)
{
    const float* magno  = (const float*)d_in[0];
    const float* line   = (const float*)d_in[1];
    const float* conv_w = (const float*)d_in[2];
    const float* conv_b = (const float*)d_in[3];
    const float* pos    = (const float*)d_in[4];
    const float* cls    = (const float*)d_in[5];
    const float* ln1_s  = (const float*)d_in[6];
    const float* ln1_b  = (const float*)d_in[7];
    const float* qkv_w  = (const float*)d_in[8];
    const float* qkv_b  = (const float*)d_in[9];
    const float* proj_w = (const float*)d_in[10];
    const float* proj_b = (const float*)d_in[11];
    const float* ln2_s  = (const float*)d_in[12];
    const float* ln2_b  = (const float*)d_in[13];
    const float* fc1_w  = (const float*)d_in[14];
    const float* fc1_b  = (const float*)d_in[15];
    const float* fc2_w  = (const float*)d_in[16];
    const float* fc2_b  = (const float*)d_in[17];
    const float* normf_s = (const float*)d_in[18];
    const float* normf_b = (const float*)d_in[19];
    const float* head_w = (const float*)d_in[20];
    const float* head_b = (const float*)d_in[21];
    float* out = (float*)d_out;
    (void)in_sizes; (void)n_in; (void)out_size; (void)ws_size;

    // workspace layout (bytes), total ~46.8 MB
    char* ws = (char*)d_ws;
    int*            idx     = (int*)            (ws + 0);         //    36864 (pad)
    float*          h       = (float*)          (ws + 147456);    //  7127040
    __hip_bfloat16* y       = (__hip_bfloat16*) (ws + 7274496);   //  3563520
    __hip_bfloat16* qk      = (__hip_bfloat16*) (ws + 10838016);  //  7127040
    __hip_bfloat16* Vt      = (__hip_bfloat16*) (ws + 17965056);  //  3932160
    __hip_bfloat16* tbuf    = (__hip_bfloat16*) (ws + 21897216);  // 14254080
    __hip_bfloat16* wt_qkv  = (__hip_bfloat16*) (ws + 36151296);  //  2654208
    __hip_bfloat16* wt_proj = (__hip_bfloat16*) (ws + 38805504);  //   884736
    __hip_bfloat16* wt_fc1  = (__hip_bfloat16*) (ws + 39690240);  //  3538944
    __hip_bfloat16* wt_fc2  = (__hip_bfloat16*) (ws + 43229184);  //  3538944
    float*          scoresbuf = (float*)qk;             // alias (used before qk)
    __hip_bfloat16* convT     = y;                      // alias (used before y)
    __hip_bfloat16* selp      = tbuf;                   // alias (used before tbuf)

    // ---- prep: weights -> bf16 [N][K]; zero Vt pads once ----
    hipMemsetAsync(Vt, 0, 3932160, stream);
    transpose_w_kernel<<<dim3(18, 6, 12), 256, 0, stream>>>(qkv_w, wt_qkv, DIM, 576);
    transpose_w_kernel<<<dim3(6, 6, 12),  256, 0, stream>>>(proj_w, wt_proj, DIM, DIM);
    transpose_w_kernel<<<dim3(24, 6, 12), 256, 0, stream>>>(fc1_w, wt_fc1, DIM, HIDN);
    transpose_w_kernel<<<dim3(6, 24, 12), 256, 0, stream>>>(fc2_w, wt_fc2, HIDN, DIM);
    convert_bf16_kernel<<<576, 256, 0, stream>>>(conv_w, convT, DIM * 768);

    // ---- patch selection + embed ----
    scores_kernel<<<Bsz * NPATCH, 256, 0, stream>>>(line, scoresbuf);
    topk_kernel<<<Bsz, 256, 0, stream>>>(scoresbuf, idx);
    gather_kernel<<<Bsz * KSEL, 256, 0, stream>>>(magno, idx, selp);
    cls_kernel<<<Bsz, DIM, 0, stream>>>(cls, pos, h);
    gemm_bf16<3><<<dim3(3, 144), 256, 0, stream>>>(selp, convT, conv_b, h,
                                                   9216, DIM, 768, idx, pos);

    const int ntok = Bsz * SEQ;              // 9280 = 145*64
    ln_kernel<<<ntok / 4, 256, 0, stream>>>(h, ln1_s, ln1_b, y, ntok);
    for (int l = 0; l < 12; ++l) {
        gemm_qkv<<<dim3(9, 145), 256, 0, stream>>>(y, wt_qkv + (size_t)l * 576 * DIM,
                                                   qkv_b + l * 576, qk, Vt);
        attnproj_kernel<<<dim3(5, Bsz), 256, 0, stream>>>(qk, Vt,
                                                          wt_proj + (size_t)l * DIM * DIM,
                                                          proj_b + l * DIM, h,
                                                          ln2_s + l * DIM, ln2_b + l * DIM, y);
        gemm_bf16<2><<<dim3(12, 145), 256, 0, stream>>>(y, wt_fc1 + (size_t)l * HIDN * DIM,
                                                        fc1_b + l * HIDN, tbuf,
                                                        ntok, HIDN, DIM, nullptr, nullptr);
        if (l < 11)
            gemm_res_ln<true><<<145, 256, 0, stream>>>(tbuf, wt_fc2 + (size_t)l * DIM * HIDN,
                                                       fc2_b + l * DIM, h,
                                                       ln1_s + (l + 1) * DIM, ln1_b + (l + 1) * DIM,
                                                       y, HIDN);
        else
            gemm_res_ln<false><<<145, 256, 0, stream>>>(tbuf, wt_fc2 + (size_t)l * DIM * HIDN,
                                                        fc2_b + l * DIM, h,
                                                        nullptr, nullptr, y, HIDN);
    }
    head_kernel<<<Bsz, 256, 0, stream>>>(h, normf_s, normf_b, head_w, head_b, out);
}